// Round 15
// baseline (251.767 us; speedup 1.0000x reference)
//
#include <hip/hip_runtime.h>
#include <math.h>

#define N_NODES 50000
#define E_EDGES 800000
#define D_DIM   128
#define H_HEADS 8
#define DH_DIM  16
#define DFF     512

#define SCAN_BLOCKS 98  // 98*512 = 50176 >= N_NODES+1
#define FFN_GRID 256
#define NTILES 3125     // 50000 / 16 exactly
#define PROJ_BLOCKS 782 // ceil(50000/64)
#define FILL_BLOCKS 782 // ceil(800000/1024)
#define NODE_ITERS 5
#define KNODE_GRID 10000  // 8 heads x 1250 groups; head = bid & 7 -> XCD pin

typedef __bf16 bf16_t;
typedef bf16_t bf16x8 __attribute__((ext_vector_type(8)));
typedef float f32x4 __attribute__((ext_vector_type(4)));
typedef unsigned short u16x8 __attribute__((ext_vector_type(8)));

#define SWZ(r) (((r) & 7) << 4)

__device__ __forceinline__ float lrelu(float v) { return v > 0.f ? v : 0.01f * v; }
__device__ __forceinline__ float elu(float v) { return v > 0.f ? v : __expf(v) - 1.f; }
__device__ __forceinline__ unsigned short f2b(float f) {
    unsigned u = __float_as_uint(f);
    unsigned r = (u + 0x7FFFu + ((u >> 16) & 1u)) >> 16;
    return (unsigned short)r;
}

// ---------------- count in-degree + capture rank ----------------
__global__ void k_count(const int* __restrict__ ed, int* __restrict__ counts,
                        int* __restrict__ rank) {
    int e = blockIdx.x * 256 + threadIdx.x;
    if (e < E_EDGES) rank[e] = atomicAdd(&counts[ed[e]], 1);
}

// ---------------- hierarchical scan ----------------
__global__ __launch_bounds__(512) void k_scan1(const int* __restrict__ counts,
                                               int* __restrict__ bsum) {
    int i = blockIdx.x * 512 + threadIdx.x;
    int v = (i < N_NODES) ? counts[i] : 0;
    #pragma unroll
    for (int o = 1; o < 64; o <<= 1) v += __shfl_xor(v, o);
    __shared__ int ws[8];
    if ((threadIdx.x & 63) == 0) ws[threadIdx.x >> 6] = v;
    __syncthreads();
    if (threadIdx.x == 0) {
        int s = 0;
        #pragma unroll
        for (int k = 0; k < 8; ++k) s += ws[k];
        bsum[blockIdx.x] = s;
    }
}

__global__ __launch_bounds__(128) void k_scan2(const int* __restrict__ bsum,
                                               int* __restrict__ boff) {
    __shared__ int tmp[128];
    int t = threadIdx.x;
    int v = (t < SCAN_BLOCKS) ? bsum[t] : 0;
    tmp[t] = v;
    __syncthreads();
    for (int o = 1; o < 128; o <<= 1) {
        int u = (t >= o) ? tmp[t - o] : 0;
        __syncthreads();
        tmp[t] += u;
        __syncthreads();
    }
    boff[t] = (t == 0) ? 0 : tmp[t - 1];
}

__global__ __launch_bounds__(512) void k_scan3(const int* __restrict__ counts,
                                               const int* __restrict__ boff,
                                               int* __restrict__ csr_off) {
    int t = threadIdx.x;
    int i = blockIdx.x * 512 + t;
    int v = (i < N_NODES) ? counts[i] : 0;
    int lane = t & 63, w = t >> 6;
    int xs = v;
    #pragma unroll
    for (int o = 1; o < 64; o <<= 1) {
        int u = __shfl_up(xs, o);
        if (lane >= o) xs += u;
    }
    __shared__ int ws[8];
    __shared__ int wo[8];
    if (lane == 63) ws[w] = xs;
    __syncthreads();
    if (t == 0) {
        int s = 0;
        #pragma unroll
        for (int k = 0; k < 8; ++k) { wo[k] = s; s += ws[k]; }
    }
    __syncthreads();
    int excl = xs - v + wo[w] + boff[blockIdx.x];
    if (i < N_NODES) csr_off[i] = excl;
    if (i == N_NODES) csr_off[N_NODES] = E_EDGES;
}

// ---------------- weight prep: transpose + bf16 (+ fused counts zero) -------
__global__ void k_prep(const float* __restrict__ W1, const float* __restrict__ W2,
                       const float* __restrict__ Wfc,
                       bf16_t* __restrict__ W1T, bf16_t* __restrict__ W2T,
                       bf16_t* __restrict__ WpT, int* __restrict__ counts) {
    int id = blockIdx.x * 256 + threadIdx.x;
    if (id < N_NODES) counts[id] = 0;
    if (id < 512 * 128) {
        int c = id >> 7, k = id & 127;
        W1T[id] = (bf16_t)W1[(size_t)k * 512 + c];
        int c2 = id >> 9, k2 = id & 511;
        W2T[id] = (bf16_t)W2[(size_t)k2 * 128 + c2];
        if (id < 128 * 128) {
            int cp = id >> 7, kp = id & 127;
            WpT[id] = (bf16_t)Wfc[(cp >> 4) * 2048 + kp * 16 + (cp & 15)];
        }
    }
}

// ---------------- FUSED: proj (MFMA) blocks || CSR-fill (scatter) blocks ----
// el/er written TRANSPOSED (head-major) for the head-partitioned k_node.
__global__ __launch_bounds__(512) void k_fillproj(const float* __restrict__ x,
                                                  const bf16_t* __restrict__ WpT,
                                                  const float* __restrict__ a_l,
                                                  const float* __restrict__ a_r,
                                                  unsigned short* __restrict__ zb,
                                                  float* __restrict__ elT,
                                                  float* __restrict__ erT,
                                                  const int* __restrict__ es,
                                                  const int* __restrict__ ed,
                                                  const int* __restrict__ rank,
                                                  const int* __restrict__ csr_off,
                                                  int* __restrict__ csr_src) {
    __shared__ char xbA[16384];  // bf16[64][128], row stride 256B, swizzled
    int t = threadIdx.x;

    if (blockIdx.x >= PROJ_BLOCKS) {
        // ---- fill branch: 1024 edges/block, no atomics ----
        int e0 = (blockIdx.x - PROJ_BLOCKS) * 1024 + t;
        #pragma unroll
        for (int k = 0; k < 2; ++k) {
            int e = e0 + k * 512;
            if (e < E_EDGES) {
                int d = ed[e];
                csr_src[csr_off[d] + rank[e]] = es[e];
            }
        }
        return;
    }

    // ---- proj branch ----
    int r0 = blockIdx.x * 64;
    {
        int r = t >> 3, c0 = (t & 7) * 16;
        int gr = r0 + r;
        u16x8 pk0, pk1;
        if (gr < N_NODES) {
            #pragma unroll
            for (int q = 0; q < 2; ++q) {
                float4 a4 = *(const float4*)&x[(size_t)gr * 128 + c0 + q * 8];
                float4 b4 = *(const float4*)&x[(size_t)gr * 128 + c0 + q * 8 + 4];
                u16x8 pk;
                pk[0] = f2b(a4.x); pk[1] = f2b(a4.y); pk[2] = f2b(a4.z); pk[3] = f2b(a4.w);
                pk[4] = f2b(b4.x); pk[5] = f2b(b4.y); pk[6] = f2b(b4.z); pk[7] = f2b(b4.w);
                if (q == 0) pk0 = pk; else pk1 = pk;
            }
        } else {
            #pragma unroll
            for (int i = 0; i < 8; ++i) { pk0[i] = 0; pk1[i] = 0; }
        }
        int base = r * 256 + c0 * 2;
        *(u16x8*)(xbA + (base ^ SWZ(r))) = pk0;
        *(u16x8*)(xbA + ((base + 16) ^ SWZ(r))) = pk1;
    }
    __syncthreads();

    int wv = t >> 6, l = t & 63;
    int lr = l & 15, lg = l >> 4;

    f32x4 acc[4] = {};
    #pragma unroll
    for (int ks = 0; ks < 4; ++ks) {
        bf16x8 b = *(const bf16x8*)(WpT + (wv * 16 + lr) * 128 + ks * 32 + lg * 8);
        #pragma unroll
        for (int mi = 0; mi < 4; ++mi) {
            int row = mi * 16 + lr;
            int off = (row * 256 + ks * 64 + lg * 16) ^ SWZ(row);
            bf16x8 a = *(const bf16x8*)(xbA + off);
            acc[mi] = __builtin_amdgcn_mfma_f32_16x16x32_bf16(a, b, acc[mi], 0, 0, 0);
        }
    }

    float alv = a_l[wv * 16 + lr];
    float arv = a_r[wv * 16 + lr];
    float outL = 0.f, outR = 0.f;
    #pragma unroll
    for (int mi = 0; mi < 4; ++mi) {
        #pragma unroll
        for (int rg = 0; rg < 4; ++rg) {
            int row = mi * 16 + lg * 4 + rg;
            int grr = r0 + row;
            float v = acc[mi][rg];
            if (grr < N_NODES) zb[(size_t)grr * 128 + wv * 16 + lr] = f2b(v);
            float pl = v * alv, pr = v * arv;
            pl += __shfl_xor(pl, 1); pr += __shfl_xor(pr, 1);
            pl += __shfl_xor(pl, 2); pr += __shfl_xor(pr, 2);
            pl += __shfl_xor(pl, 4); pr += __shfl_xor(pr, 4);
            pl += __shfl_xor(pl, 8); pr += __shfl_xor(pr, 8);
            if (lr == mi * 4 + rg) { outL = pl; outR = pr; }
        }
    }
    int myrow = r0 + (lr >> 2) * 16 + lg * 4 + (lr & 3);
    if (myrow < N_NODES) {
        elT[(size_t)wv * N_NODES + myrow] = outL;
        erT[(size_t)wv * N_NODES + myrow] = outR;
    }
}

// ---------------- head-partitioned softmax+aggregate+elu+residual -----------
// head = blockIdx & 7 -> pinned to one XCD (round-robin dispatch): per-XCD
// working set = zb[:,h-slice] 1.6MB + elT[h] 200KB < 4MB L2 -> gathers hit L2.
// 32 lanes/node: 4 edge slots x 8 dim-pairs. Same-slot lanes broadcast-load
// csr/el; 8 dim-pair lanes gather one coalesced 32B zb segment per edge.
__global__ __launch_bounds__(256) void k_node(const int* __restrict__ csr_off,
                                              const int* __restrict__ csr_src,
                                              const float* __restrict__ elT,
                                              const float* __restrict__ erT,
                                              const unsigned short* __restrict__ zb,
                                              const float* __restrict__ x,
                                              float* __restrict__ out) {
    int h = blockIdx.x & 7;
    int grp = blockIdx.x >> 3;
    int t = threadIdx.x;
    int hw = t >> 5;             // half-wave = node
    int q = t & 31;
    int s = q >> 3, dp = q & 7;  // edge slot, dim pair
    const float* elh = elT + (size_t)h * N_NODES;
    const float* erh = erT + (size_t)h * N_NODES;
    const unsigned short* zbh = zb + h * 16 + dp * 2;

    for (int it = 0; it < NODE_ITERS; ++it) {
        int n = (grp * NODE_ITERS + it) * 8 + hw;
        int row = csr_off[n];
        int deg = csr_off[n + 1] - row;
        float erv = erh[n];
        float ps = 0.f, a0 = 0.f, a1 = 0.f;
        #pragma unroll
        for (int c = 0; c < 8; ++c) {
            if (c * 4 < deg) {  // uniform across half-wave
                int k = c * 4 + s;
                int kk = min(k, deg - 1);
                int src = csr_src[row + kk];
                float e = lrelu(elh[src] + erv);
                float p = (k < deg) ? __expf(e) : 0.f;
                ps += p;
                unsigned u = *(const unsigned*)(zbh + (size_t)src * 128);
                a0 += p * __uint_as_float(u << 16);
                a1 += p * __uint_as_float(u & 0xFFFF0000u);
            }
        }
        int nch = (deg + 3) >> 2;
        for (int c = 8; c < nch; ++c) {  // rare: deg > 32
            int k = c * 4 + s;
            int kk = min(k, deg - 1);
            int src = csr_src[row + kk];
            float e = lrelu(elh[src] + erv);
            float p = (k < deg) ? __expf(e) : 0.f;
            ps += p;
            unsigned u = *(const unsigned*)(zbh + (size_t)src * 128);
            a0 += p * __uint_as_float(u << 16);
            a1 += p * __uint_as_float(u & 0xFFFF0000u);
        }
        // reduce across the 4 edge slots (bits 3,4 of q)
        ps += __shfl_xor(ps, 8);  ps += __shfl_xor(ps, 16);
        a0 += __shfl_xor(a0, 8);  a0 += __shfl_xor(a0, 16);
        a1 += __shfl_xor(a1, 8);  a1 += __shfl_xor(a1, 16);
        if (s == 0) {
            float inv = 1.f / fmaxf(ps, 1e-9f);
            float2 xv = *(const float2*)&x[(size_t)n * 128 + h * 16 + dp * 2];
            float2 hv;
            hv.x = xv.x + elu(a0 * inv);
            hv.y = xv.y + elu(a1 * inv);
            *(float2*)&out[(size_t)n * 128 + h * 16 + dp * 2] = hv;
        }
    }
}

// ---------------- FFN: weight-stationary persistent kernel + in-reg LN ------
// LN moved here (head-split k_node can't see full rows): h fragments loaded
// f32, stats via shfl_xor(16/32) across the 4 lg-lanes, pack bf16 B-frags.
__global__ __launch_bounds__(256, 1) void k_ffn(const bf16_t* __restrict__ W1T,
                                                const float* __restrict__ b1,
                                                const bf16_t* __restrict__ W2T,
                                                const float* __restrict__ b2,
                                                const float* __restrict__ gamma,
                                                const float* __restrict__ beta,
                                                float* __restrict__ out) {
    __shared__ char inA[16384];  // bf16[16 nodes][512 f], row 1024B, swz by node
    int t = threadIdx.x;
    int w = t >> 6, l = t & 63;
    int lr = l & 15, lg = l >> 4;

    bf16x8 w1f[4][8];
    #pragma unroll
    for (int ks = 0; ks < 4; ++ks)
        #pragma unroll
        for (int tf = 0; tf < 8; ++tf)
            w1f[ks][tf] = *(const bf16x8*)(W1T + (size_t)(w * 128 + tf * 16 + lr) * 128 + ks * 32 + lg * 8);
    bf16x8 w2f[16][2];
    #pragma unroll
    for (int ks2 = 0; ks2 < 16; ++ks2)
        #pragma unroll
        for (int tc = 0; tc < 2; ++tc)
            w2f[ks2][tc] = *(const bf16x8*)(W2T + (size_t)(w * 32 + tc * 16 + lr) * 512 + ks2 * 32 + lg * 8);
    float4 b1v[8];
    #pragma unroll
    for (int tf = 0; tf < 8; ++tf)
        b1v[tf] = *(const float4*)&b1[w * 128 + tf * 16 + lg * 4];
    float4 b2v[2];
    #pragma unroll
    for (int tc = 0; tc < 2; ++tc)
        b2v[tc] = *(const float4*)&b2[w * 32 + tc * 16 + lg * 4];

    int tile = blockIdx.x;
    while (tile < NTILES) {
        const float* hbase = out + (size_t)(tile * 16 + lr) * 128;
        float4 h4[2];
        #pragma unroll
        for (int tc = 0; tc < 2; ++tc)
            h4[tc] = *(const float4*)(hbase + w * 32 + tc * 16 + lg * 4);

        // h fragments + in-register LN
        float hvv[4][8];
        float sm = 0.f, sq = 0.f;
        #pragma unroll
        for (int ks = 0; ks < 4; ++ks) {
            float4 A = *(const float4*)(hbase + ks * 32 + lg * 8);
            float4 B = *(const float4*)(hbase + ks * 32 + lg * 8 + 4);
            hvv[ks][0] = A.x; hvv[ks][1] = A.y; hvv[ks][2] = A.z; hvv[ks][3] = A.w;
            hvv[ks][4] = B.x; hvv[ks][5] = B.y; hvv[ks][6] = B.z; hvv[ks][7] = B.w;
            #pragma unroll
            for (int j = 0; j < 8; ++j) { sm += hvv[ks][j]; sq += hvv[ks][j] * hvv[ks][j]; }
        }
        sm += __shfl_xor(sm, 16); sq += __shfl_xor(sq, 16);
        sm += __shfl_xor(sm, 32); sq += __shfl_xor(sq, 32);
        float mu = sm * (1.f / 128.f);
        float rs = rsqrtf(sq * (1.f / 128.f) - mu * mu + 1e-5f);
        bf16x8 cur[4];
        #pragma unroll
        for (int ks = 0; ks < 4; ++ks) {
            float4 g0 = *(const float4*)&gamma[ks * 32 + lg * 8];
            float4 g1 = *(const float4*)&gamma[ks * 32 + lg * 8 + 4];
            float4 be0 = *(const float4*)&beta[ks * 32 + lg * 8];
            float4 be1 = *(const float4*)&beta[ks * 32 + lg * 8 + 4];
            float ga[8] = {g0.x, g0.y, g0.z, g0.w, g1.x, g1.y, g1.z, g1.w};
            float ba[8] = {be0.x, be0.y, be0.z, be0.w, be1.x, be1.y, be1.z, be1.w};
            u16x8 pk;
            #pragma unroll
            for (int j = 0; j < 8; ++j)
                pk[j] = f2b((hvv[ks][j] - mu) * rs * ga[j] + ba[j]);
            cur[ks] = __builtin_bit_cast(bf16x8, pk);
        }

        f32x4 p[8] = {};
        #pragma unroll
        for (int ks = 0; ks < 4; ++ks)
            #pragma unroll
            for (int tf = 0; tf < 8; ++tf)
                p[tf] = __builtin_amdgcn_mfma_f32_16x16x32_bf16(w1f[ks][tf], cur[ks], p[tf], 0, 0, 0);

        #pragma unroll
        for (int tf = 0; tf < 8; ++tf) {
            float4 bb = b1v[tf];
            ushort4 pk;
            float v0 = p[tf][0] + bb.x; pk.x = f2b(v0 > 0.f ? v0 : 0.f);
            float v1 = p[tf][1] + bb.y; pk.y = f2b(v1 > 0.f ? v1 : 0.f);
            float v2 = p[tf][2] + bb.z; pk.z = f2b(v2 > 0.f ? v2 : 0.f);
            float v3 = p[tf][3] + bb.w; pk.w = f2b(v3 > 0.f ? v3 : 0.f);
            *(ushort4*)(inA + ((lr * 1024 + w * 256 + tf * 32 + lg * 8) ^ SWZ(lr))) = pk;
        }
        __syncthreads();

        f32x4 Q[2] = {};
        #pragma unroll
        for (int ks2 = 0; ks2 < 16; ++ks2) {
            bf16x8 bfr = *(const bf16x8*)(inA + ((lr * 1024 + ks2 * 64 + lg * 16) ^ SWZ(lr)));
            #pragma unroll
            for (int tc = 0; tc < 2; ++tc)
                Q[tc] = __builtin_amdgcn_mfma_f32_16x16x32_bf16(w2f[ks2][tc], bfr, Q[tc], 0, 0, 0);
        }

        #pragma unroll
        for (int tc = 0; tc < 2; ++tc) {
            float4 o4;
            o4.x = Q[tc][0] + b2v[tc].x + h4[tc].x;
            o4.y = Q[tc][1] + b2v[tc].y + h4[tc].y;
            o4.z = Q[tc][2] + b2v[tc].z + h4[tc].z;
            o4.w = Q[tc][3] + b2v[tc].w + h4[tc].w;
            *(float4*)(out + (size_t)(tile * 16 + lr) * 128 + w * 32 + tc * 16 + lg * 4) = o4;
        }
        __syncthreads();
        tile += FFN_GRID;
    }
}

extern "C" void kernel_launch(void* const* d_in, const int* in_sizes, int n_in,
                              void* d_out, int out_size, void* d_ws, size_t ws_size,
                              hipStream_t stream) {
    const float* x     = (const float*)d_in[0];
    const float* Wfc   = (const float*)d_in[1];
    const float* a_l   = (const float*)d_in[2];
    const float* a_r   = (const float*)d_in[3];
    const float* gamma = (const float*)d_in[4];
    const float* beta  = (const float*)d_in[5];
    const float* W1    = (const float*)d_in[6];
    const float* b1    = (const float*)d_in[7];
    const float* W2    = (const float*)d_in[8];
    const float* b2    = (const float*)d_in[9];
    const int*   es    = (const int*)d_in[10];
    const int*   ed    = (const int*)d_in[11];
    float* out = (float*)d_out;

    bf16_t* W1T = (bf16_t*)d_ws;                      // 512*128
    bf16_t* W2T = W1T + 512 * 128;                    // 128*512
    bf16_t* WpT = W2T + 128 * 512;                    // 128*128
    unsigned short* zb = (unsigned short*)(WpT + 128 * 128);  // N*128 bf16
    float* elT = (float*)(zb + (size_t)N_NODES * 128);  // 8*N (head-major)
    float* erT = elT + (size_t)8 * N_NODES;             // 8*N
    int* counts  = (int*)(erT + (size_t)8 * N_NODES);   // N
    int* csr_off = counts + N_NODES;                  // N+1
    int* csr_src = csr_off + N_NODES + 1;             // E
    int* rank    = csr_src + E_EDGES;                 // E
    int* bsum    = rank + E_EDGES;                    // 128
    int* boff    = bsum + 128;                        // 128

    k_prep<<<dim3(256), dim3(256), 0, stream>>>(W1, W2, Wfc, W1T, W2T, WpT, counts);
    k_count<<<dim3((E_EDGES + 255) / 256), dim3(256), 0, stream>>>(ed, counts, rank);
    k_scan1<<<dim3(SCAN_BLOCKS), dim3(512), 0, stream>>>(counts, bsum);
    k_scan2<<<dim3(1), dim3(128), 0, stream>>>(bsum, boff);
    k_scan3<<<dim3(SCAN_BLOCKS), dim3(512), 0, stream>>>(counts, boff, csr_off);
    k_fillproj<<<dim3(PROJ_BLOCKS + FILL_BLOCKS), dim3(512), 0, stream>>>(
        x, WpT, a_l, a_r, zb, elT, erT, es, ed, rank, csr_off, csr_src);
    k_node<<<dim3(KNODE_GRID), dim3(256), 0, stream>>>(csr_off, csr_src, elT, erT, zb, x, out);
    k_ffn<<<dim3(FFN_GRID), dim3(256), 0, stream>>>(W1T, b1, W2T, b2, gamma, beta, out);
}

// Round 16
// 229.365 us; speedup vs baseline: 1.0977x; 1.0977x over previous
//
#include <hip/hip_runtime.h>
#include <math.h>

#define N_NODES 50000
#define E_EDGES 800000
#define D_DIM   128
#define H_HEADS 8
#define DH_DIM  16
#define DFF     512

#define SCAN_BLOCKS 98  // 98*512 = 50176 >= N_NODES+1
#define FFN_GRID 256
#define NTILES 3125     // 50000 / 16 exactly
#define PROJ_BLOCKS 782 // ceil(50000/64)
#define FILL_BLOCKS 782 // ceil(800000/1024)
#define NODE_ITERS 5
#define KNODE_GRID 10000  // 8 heads x 1250 groups; head = bid & 7 -> XCD pin

typedef __bf16 bf16_t;
typedef bf16_t bf16x8 __attribute__((ext_vector_type(8)));
typedef float f32x4 __attribute__((ext_vector_type(4)));
typedef unsigned short u16x8 __attribute__((ext_vector_type(8)));

#define SWZ(r) (((r) & 7) << 4)

__device__ __forceinline__ float lrelu(float v) { return v > 0.f ? v : 0.01f * v; }
__device__ __forceinline__ float elu(float v) { return v > 0.f ? v : __expf(v) - 1.f; }
__device__ __forceinline__ unsigned short f2b(float f) {
    unsigned u = __float_as_uint(f);
    unsigned r = (u + 0x7FFFu + ((u >> 16) & 1u)) >> 16;
    return (unsigned short)r;
}

// ---------------- count in-degree + capture rank ----------------
__global__ void k_count(const int* __restrict__ ed, int* __restrict__ counts,
                        int* __restrict__ rank) {
    int e = blockIdx.x * 256 + threadIdx.x;
    if (e < E_EDGES) rank[e] = atomicAdd(&counts[ed[e]], 1);
}

// ---------------- hierarchical scan ----------------
__global__ __launch_bounds__(512) void k_scan1(const int* __restrict__ counts,
                                               int* __restrict__ bsum) {
    int i = blockIdx.x * 512 + threadIdx.x;
    int v = (i < N_NODES) ? counts[i] : 0;
    #pragma unroll
    for (int o = 1; o < 64; o <<= 1) v += __shfl_xor(v, o);
    __shared__ int ws[8];
    if ((threadIdx.x & 63) == 0) ws[threadIdx.x >> 6] = v;
    __syncthreads();
    if (threadIdx.x == 0) {
        int s = 0;
        #pragma unroll
        for (int k = 0; k < 8; ++k) s += ws[k];
        bsum[blockIdx.x] = s;
    }
}

__global__ __launch_bounds__(128) void k_scan2(const int* __restrict__ bsum,
                                               int* __restrict__ boff) {
    __shared__ int tmp[128];
    int t = threadIdx.x;
    int v = (t < SCAN_BLOCKS) ? bsum[t] : 0;
    tmp[t] = v;
    __syncthreads();
    for (int o = 1; o < 128; o <<= 1) {
        int u = (t >= o) ? tmp[t - o] : 0;
        __syncthreads();
        tmp[t] += u;
        __syncthreads();
    }
    boff[t] = (t == 0) ? 0 : tmp[t - 1];
}

__global__ __launch_bounds__(512) void k_scan3(const int* __restrict__ counts,
                                               const int* __restrict__ boff,
                                               int* __restrict__ csr_off) {
    int t = threadIdx.x;
    int i = blockIdx.x * 512 + t;
    int v = (i < N_NODES) ? counts[i] : 0;
    int lane = t & 63, w = t >> 6;
    int xs = v;
    #pragma unroll
    for (int o = 1; o < 64; o <<= 1) {
        int u = __shfl_up(xs, o);
        if (lane >= o) xs += u;
    }
    __shared__ int ws[8];
    __shared__ int wo[8];
    if (lane == 63) ws[w] = xs;
    __syncthreads();
    if (t == 0) {
        int s = 0;
        #pragma unroll
        for (int k = 0; k < 8; ++k) { wo[k] = s; s += ws[k]; }
    }
    __syncthreads();
    int excl = xs - v + wo[w] + boff[blockIdx.x];
    if (i < N_NODES) csr_off[i] = excl;
    if (i == N_NODES) csr_off[N_NODES] = E_EDGES;
}

// ---------------- weight prep: transpose + bf16 (+ fused counts zero) -------
__global__ void k_prep(const float* __restrict__ W1, const float* __restrict__ W2,
                       const float* __restrict__ Wfc,
                       bf16_t* __restrict__ W1T, bf16_t* __restrict__ W2T,
                       bf16_t* __restrict__ WpT, int* __restrict__ counts) {
    int id = blockIdx.x * 256 + threadIdx.x;
    if (id < N_NODES) counts[id] = 0;
    if (id < 512 * 128) {
        int c = id >> 7, k = id & 127;
        W1T[id] = (bf16_t)W1[(size_t)k * 512 + c];
        int c2 = id >> 9, k2 = id & 511;
        W2T[id] = (bf16_t)W2[(size_t)k2 * 128 + c2];
        if (id < 128 * 128) {
            int cp = id >> 7, kp = id & 127;
            WpT[id] = (bf16_t)Wfc[(cp >> 4) * 2048 + kp * 16 + (cp & 15)];
        }
    }
}

// ---------------- FUSED: proj (MFMA) blocks || CSR-fill (scatter) blocks ----
// z written HEAD-MAJOR: zbT[h][node][16] so each head's table is a contiguous
// 1.6MB block (one XCD's L2). el/er head-major too.
__global__ __launch_bounds__(512) void k_fillproj(const float* __restrict__ x,
                                                  const bf16_t* __restrict__ WpT,
                                                  const float* __restrict__ a_l,
                                                  const float* __restrict__ a_r,
                                                  unsigned short* __restrict__ zbT,
                                                  float* __restrict__ elT,
                                                  float* __restrict__ erT,
                                                  const int* __restrict__ es,
                                                  const int* __restrict__ ed,
                                                  const int* __restrict__ rank,
                                                  const int* __restrict__ csr_off,
                                                  int* __restrict__ csr_src) {
    __shared__ char xbA[16384];  // bf16[64][128], row stride 256B, swizzled
    int t = threadIdx.x;

    if (blockIdx.x >= PROJ_BLOCKS) {
        // ---- fill branch: 1024 edges/block, no atomics ----
        int e0 = (blockIdx.x - PROJ_BLOCKS) * 1024 + t;
        #pragma unroll
        for (int k = 0; k < 2; ++k) {
            int e = e0 + k * 512;
            if (e < E_EDGES) {
                int d = ed[e];
                csr_src[csr_off[d] + rank[e]] = es[e];
            }
        }
        return;
    }

    // ---- proj branch ----
    int r0 = blockIdx.x * 64;
    {
        int r = t >> 3, c0 = (t & 7) * 16;
        int gr = r0 + r;
        u16x8 pk0, pk1;
        if (gr < N_NODES) {
            #pragma unroll
            for (int q = 0; q < 2; ++q) {
                float4 a4 = *(const float4*)&x[(size_t)gr * 128 + c0 + q * 8];
                float4 b4 = *(const float4*)&x[(size_t)gr * 128 + c0 + q * 8 + 4];
                u16x8 pk;
                pk[0] = f2b(a4.x); pk[1] = f2b(a4.y); pk[2] = f2b(a4.z); pk[3] = f2b(a4.w);
                pk[4] = f2b(b4.x); pk[5] = f2b(b4.y); pk[6] = f2b(b4.z); pk[7] = f2b(b4.w);
                if (q == 0) pk0 = pk; else pk1 = pk;
            }
        } else {
            #pragma unroll
            for (int i = 0; i < 8; ++i) { pk0[i] = 0; pk1[i] = 0; }
        }
        int base = r * 256 + c0 * 2;
        *(u16x8*)(xbA + (base ^ SWZ(r))) = pk0;
        *(u16x8*)(xbA + ((base + 16) ^ SWZ(r))) = pk1;
    }
    __syncthreads();

    int wv = t >> 6, l = t & 63;
    int lr = l & 15, lg = l >> 4;

    f32x4 acc[4] = {};
    #pragma unroll
    for (int ks = 0; ks < 4; ++ks) {
        bf16x8 b = *(const bf16x8*)(WpT + (wv * 16 + lr) * 128 + ks * 32 + lg * 8);
        #pragma unroll
        for (int mi = 0; mi < 4; ++mi) {
            int row = mi * 16 + lr;
            int off = (row * 256 + ks * 64 + lg * 16) ^ SWZ(row);
            bf16x8 a = *(const bf16x8*)(xbA + off);
            acc[mi] = __builtin_amdgcn_mfma_f32_16x16x32_bf16(a, b, acc[mi], 0, 0, 0);
        }
    }

    float alv = a_l[wv * 16 + lr];
    float arv = a_r[wv * 16 + lr];
    float outL = 0.f, outR = 0.f;
    #pragma unroll
    for (int mi = 0; mi < 4; ++mi) {
        #pragma unroll
        for (int rg = 0; rg < 4; ++rg) {
            int row = mi * 16 + lg * 4 + rg;
            int grr = r0 + row;
            float v = acc[mi][rg];
            if (grr < N_NODES)
                zbT[((size_t)wv * N_NODES + grr) * 16 + lr] = f2b(v);
            float pl = v * alv, pr = v * arv;
            pl += __shfl_xor(pl, 1); pr += __shfl_xor(pr, 1);
            pl += __shfl_xor(pl, 2); pr += __shfl_xor(pr, 2);
            pl += __shfl_xor(pl, 4); pr += __shfl_xor(pr, 4);
            pl += __shfl_xor(pl, 8); pr += __shfl_xor(pr, 8);
            if (lr == mi * 4 + rg) { outL = pl; outR = pr; }
        }
    }
    int myrow = r0 + (lr >> 2) * 16 + lg * 4 + (lr & 3);
    if (myrow < N_NODES) {
        elT[(size_t)wv * N_NODES + myrow] = outL;
        erT[(size_t)wv * N_NODES + myrow] = outR;
    }
}

// ---------------- head-partitioned softmax+aggregate+elu+residual -----------
// head = blockIdx & 7 -> XCD pin. Per-XCD resident: zbT[h] 1.6MB (contiguous,
// head-major) + elT[h] 200KB < 4MB L2. 32 lanes/node: 4 edge slots x 8
// dim-pairs; per edge the 8 dp-lanes gather one contiguous 32B segment.
__global__ __launch_bounds__(256) void k_node(const int* __restrict__ csr_off,
                                              const int* __restrict__ csr_src,
                                              const float* __restrict__ elT,
                                              const float* __restrict__ erT,
                                              const unsigned short* __restrict__ zbT,
                                              const float* __restrict__ x,
                                              float* __restrict__ out) {
    int h = blockIdx.x & 7;
    int grp = blockIdx.x >> 3;
    int t = threadIdx.x;
    int hw = t >> 5;             // half-wave = node
    int q = t & 31;
    int s = q >> 3, dp = q & 7;  // edge slot, dim pair
    const float* elh = elT + (size_t)h * N_NODES;
    const float* erh = erT + (size_t)h * N_NODES;
    const unsigned short* zbh = zbT + (size_t)h * N_NODES * 16 + dp * 2;

    for (int it = 0; it < NODE_ITERS; ++it) {
        int n = (grp * NODE_ITERS + it) * 8 + hw;
        int row = csr_off[n];
        int deg = csr_off[n + 1] - row;
        float erv = erh[n];
        float ps = 0.f, a0 = 0.f, a1 = 0.f;
        #pragma unroll
        for (int c = 0; c < 8; ++c) {
            if (c * 4 < deg) {  // uniform across half-wave
                int k = c * 4 + s;
                int kk = min(k, deg - 1);
                int src = csr_src[row + kk];
                float e = lrelu(elh[src] + erv);
                float p = (k < deg) ? __expf(e) : 0.f;
                ps += p;
                unsigned u = *(const unsigned*)(zbh + (size_t)src * 16);
                a0 += p * __uint_as_float(u << 16);
                a1 += p * __uint_as_float(u & 0xFFFF0000u);
            }
        }
        int nch = (deg + 3) >> 2;
        for (int c = 8; c < nch; ++c) {  // rare: deg > 32
            int k = c * 4 + s;
            int kk = min(k, deg - 1);
            int src = csr_src[row + kk];
            float e = lrelu(elh[src] + erv);
            float p = (k < deg) ? __expf(e) : 0.f;
            ps += p;
            unsigned u = *(const unsigned*)(zbh + (size_t)src * 16);
            a0 += p * __uint_as_float(u << 16);
            a1 += p * __uint_as_float(u & 0xFFFF0000u);
        }
        // reduce across the 4 edge slots (bits 3,4 of q)
        ps += __shfl_xor(ps, 8);  ps += __shfl_xor(ps, 16);
        a0 += __shfl_xor(a0, 8);  a0 += __shfl_xor(a0, 16);
        a1 += __shfl_xor(a1, 8);  a1 += __shfl_xor(a1, 16);
        if (s == 0) {
            float inv = 1.f / fmaxf(ps, 1e-9f);
            float2 xv = *(const float2*)&x[(size_t)n * 128 + h * 16 + dp * 2];
            float2 hv;
            hv.x = xv.x + elu(a0 * inv);
            hv.y = xv.y + elu(a1 * inv);
            *(float2*)&out[(size_t)n * 128 + h * 16 + dp * 2] = hv;
        }
    }
}

// ---------------- FFN: weight-stationary persistent kernel + in-reg LN ------
__global__ __launch_bounds__(256, 1) void k_ffn(const bf16_t* __restrict__ W1T,
                                                const float* __restrict__ b1,
                                                const bf16_t* __restrict__ W2T,
                                                const float* __restrict__ b2,
                                                const float* __restrict__ gamma,
                                                const float* __restrict__ beta,
                                                float* __restrict__ out) {
    __shared__ char inA[16384];  // bf16[16 nodes][512 f], row 1024B, swz by node
    int t = threadIdx.x;
    int w = t >> 6, l = t & 63;
    int lr = l & 15, lg = l >> 4;

    bf16x8 w1f[4][8];
    #pragma unroll
    for (int ks = 0; ks < 4; ++ks)
        #pragma unroll
        for (int tf = 0; tf < 8; ++tf)
            w1f[ks][tf] = *(const bf16x8*)(W1T + (size_t)(w * 128 + tf * 16 + lr) * 128 + ks * 32 + lg * 8);
    bf16x8 w2f[16][2];
    #pragma unroll
    for (int ks2 = 0; ks2 < 16; ++ks2)
        #pragma unroll
        for (int tc = 0; tc < 2; ++tc)
            w2f[ks2][tc] = *(const bf16x8*)(W2T + (size_t)(w * 32 + tc * 16 + lr) * 512 + ks2 * 32 + lg * 8);
    float4 b1v[8];
    #pragma unroll
    for (int tf = 0; tf < 8; ++tf)
        b1v[tf] = *(const float4*)&b1[w * 128 + tf * 16 + lg * 4];
    float4 b2v[2];
    #pragma unroll
    for (int tc = 0; tc < 2; ++tc)
        b2v[tc] = *(const float4*)&b2[w * 32 + tc * 16 + lg * 4];

    int tile = blockIdx.x;
    while (tile < NTILES) {
        const float* hbase = out + (size_t)(tile * 16 + lr) * 128;
        float4 h4[2];
        #pragma unroll
        for (int tc = 0; tc < 2; ++tc)
            h4[tc] = *(const float4*)(hbase + w * 32 + tc * 16 + lg * 4);

        // h fragments + in-register LN
        float hvv[4][8];
        float sm = 0.f, sq = 0.f;
        #pragma unroll
        for (int ks = 0; ks < 4; ++ks) {
            float4 A = *(const float4*)(hbase + ks * 32 + lg * 8);
            float4 B = *(const float4*)(hbase + ks * 32 + lg * 8 + 4);
            hvv[ks][0] = A.x; hvv[ks][1] = A.y; hvv[ks][2] = A.z; hvv[ks][3] = A.w;
            hvv[ks][4] = B.x; hvv[ks][5] = B.y; hvv[ks][6] = B.z; hvv[ks][7] = B.w;
            #pragma unroll
            for (int j = 0; j < 8; ++j) { sm += hvv[ks][j]; sq += hvv[ks][j] * hvv[ks][j]; }
        }
        sm += __shfl_xor(sm, 16); sq += __shfl_xor(sq, 16);
        sm += __shfl_xor(sm, 32); sq += __shfl_xor(sq, 32);
        float mu = sm * (1.f / 128.f);
        float rs = rsqrtf(sq * (1.f / 128.f) - mu * mu + 1e-5f);
        bf16x8 cur[4];
        #pragma unroll
        for (int ks = 0; ks < 4; ++ks) {
            float4 g0 = *(const float4*)&gamma[ks * 32 + lg * 8];
            float4 g1 = *(const float4*)&gamma[ks * 32 + lg * 8 + 4];
            float4 be0 = *(const float4*)&beta[ks * 32 + lg * 8];
            float4 be1 = *(const float4*)&beta[ks * 32 + lg * 8 + 4];
            float ga[8] = {g0.x, g0.y, g0.z, g0.w, g1.x, g1.y, g1.z, g1.w};
            float ba[8] = {be0.x, be0.y, be0.z, be0.w, be1.x, be1.y, be1.z, be1.w};
            u16x8 pk;
            #pragma unroll
            for (int j = 0; j < 8; ++j)
                pk[j] = f2b((hvv[ks][j] - mu) * rs * ga[j] + ba[j]);
            cur[ks] = __builtin_bit_cast(bf16x8, pk);
        }

        f32x4 p[8] = {};
        #pragma unroll
        for (int ks = 0; ks < 4; ++ks)
            #pragma unroll
            for (int tf = 0; tf < 8; ++tf)
                p[tf] = __builtin_amdgcn_mfma_f32_16x16x32_bf16(w1f[ks][tf], cur[ks], p[tf], 0, 0, 0);

        #pragma unroll
        for (int tf = 0; tf < 8; ++tf) {
            float4 bb = b1v[tf];
            ushort4 pk;
            float v0 = p[tf][0] + bb.x; pk.x = f2b(v0 > 0.f ? v0 : 0.f);
            float v1 = p[tf][1] + bb.y; pk.y = f2b(v1 > 0.f ? v1 : 0.f);
            float v2 = p[tf][2] + bb.z; pk.z = f2b(v2 > 0.f ? v2 : 0.f);
            float v3 = p[tf][3] + bb.w; pk.w = f2b(v3 > 0.f ? v3 : 0.f);
            *(ushort4*)(inA + ((lr * 1024 + w * 256 + tf * 32 + lg * 8) ^ SWZ(lr))) = pk;
        }
        __syncthreads();

        f32x4 Q[2] = {};
        #pragma unroll
        for (int ks2 = 0; ks2 < 16; ++ks2) {
            bf16x8 bfr = *(const bf16x8*)(inA + ((lr * 1024 + ks2 * 64 + lg * 16) ^ SWZ(lr)));
            #pragma unroll
            for (int tc = 0; tc < 2; ++tc)
                Q[tc] = __builtin_amdgcn_mfma_f32_16x16x32_bf16(w2f[ks2][tc], bfr, Q[tc], 0, 0, 0);
        }

        #pragma unroll
        for (int tc = 0; tc < 2; ++tc) {
            float4 o4;
            o4.x = Q[tc][0] + b2v[tc].x + h4[tc].x;
            o4.y = Q[tc][1] + b2v[tc].y + h4[tc].y;
            o4.z = Q[tc][2] + b2v[tc].z + h4[tc].z;
            o4.w = Q[tc][3] + b2v[tc].w + h4[tc].w;
            *(float4*)(out + (size_t)(tile * 16 + lr) * 128 + w * 32 + tc * 16 + lg * 4) = o4;
        }
        __syncthreads();
        tile += FFN_GRID;
    }
}

extern "C" void kernel_launch(void* const* d_in, const int* in_sizes, int n_in,
                              void* d_out, int out_size, void* d_ws, size_t ws_size,
                              hipStream_t stream) {
    const float* x     = (const float*)d_in[0];
    const float* Wfc   = (const float*)d_in[1];
    const float* a_l   = (const float*)d_in[2];
    const float* a_r   = (const float*)d_in[3];
    const float* gamma = (const float*)d_in[4];
    const float* beta  = (const float*)d_in[5];
    const float* W1    = (const float*)d_in[6];
    const float* b1    = (const float*)d_in[7];
    const float* W2    = (const float*)d_in[8];
    const float* b2    = (const float*)d_in[9];
    const int*   es    = (const int*)d_in[10];
    const int*   ed    = (const int*)d_in[11];
    float* out = (float*)d_out;

    bf16_t* W1T = (bf16_t*)d_ws;                      // 512*128
    bf16_t* W2T = W1T + 512 * 128;                    // 128*512
    bf16_t* WpT = W2T + 128 * 512;                    // 128*128
    unsigned short* zbT = (unsigned short*)(WpT + 128 * 128);  // 8*N*16 bf16 (head-major)
    float* elT = (float*)(zbT + (size_t)N_NODES * 128);  // 8*N (head-major)
    float* erT = elT + (size_t)8 * N_NODES;             // 8*N
    int* counts  = (int*)(erT + (size_t)8 * N_NODES);   // N
    int* csr_off = counts + N_NODES;                  // N+1
    int* csr_src = csr_off + N_NODES + 1;             // E
    int* rank    = csr_src + E_EDGES;                 // E
    int* bsum    = rank + E_EDGES;                    // 128
    int* boff    = bsum + 128;                        // 128

    k_prep<<<dim3(256), dim3(256), 0, stream>>>(W1, W2, Wfc, W1T, W2T, WpT, counts);
    k_count<<<dim3((E_EDGES + 255) / 256), dim3(256), 0, stream>>>(ed, counts, rank);
    k_scan1<<<dim3(SCAN_BLOCKS), dim3(512), 0, stream>>>(counts, bsum);
    k_scan2<<<dim3(1), dim3(128), 0, stream>>>(bsum, boff);
    k_scan3<<<dim3(SCAN_BLOCKS), dim3(512), 0, stream>>>(counts, boff, csr_off);
    k_fillproj<<<dim3(PROJ_BLOCKS + FILL_BLOCKS), dim3(512), 0, stream>>>(
        x, WpT, a_l, a_r, zbT, elT, erT, es, ed, rank, csr_off, csr_src);
    k_node<<<dim3(KNODE_GRID), dim3(256), 0, stream>>>(csr_off, csr_src, elT, erT, zbT, x, out);
    k_ffn<<<dim3(FFN_GRID), dim3(256), 0, stream>>>(W1T, b1, W2T, b2, gamma, beta, out);
}

// Round 17
// 206.064 us; speedup vs baseline: 1.2218x; 1.1131x over previous
//
#include <hip/hip_runtime.h>
#include <math.h>

#define N_NODES 50000
#define E_EDGES 800000
#define D_DIM   128
#define H_HEADS 8
#define DH_DIM  16
#define DFF     512

#define SCAN_BLOCKS 98  // 98*512 = 50176 >= N_NODES+1
#define FFN_GRID 256
#define NTILES 3125     // 50000 / 16 exactly
#define PROJ_BLOCKS 782 // ceil(50000/64)
#define FILL_BLOCKS 782 // ceil(800000/1024)
#define NODE_ITERS 5
#define KNODE_GRID 10000  // 8 heads x 1250 groups; head = bid & 7 -> XCD pin

typedef __bf16 bf16_t;
typedef bf16_t bf16x8 __attribute__((ext_vector_type(8)));
typedef float f32x4 __attribute__((ext_vector_type(4)));
typedef unsigned short u16x8 __attribute__((ext_vector_type(8)));

#define SWZ(r) (((r) & 7) << 4)

__device__ __forceinline__ float lrelu(float v) { return v > 0.f ? v : 0.01f * v; }
__device__ __forceinline__ float elu(float v) { return v > 0.f ? v : __expf(v) - 1.f; }
__device__ __forceinline__ unsigned short f2b(float f) {
    unsigned u = __float_as_uint(f);
    unsigned r = (u + 0x7FFFu + ((u >> 16) & 1u)) >> 16;
    return (unsigned short)r;
}
__device__ __forceinline__ float bflo(unsigned w) { return __uint_as_float(w << 16); }
__device__ __forceinline__ float bfhi(unsigned w) { return __uint_as_float(w & 0xFFFF0000u); }

// ---------------- count in-degree + capture rank ----------------
__global__ void k_count(const int* __restrict__ ed, int* __restrict__ counts,
                        int* __restrict__ rank) {
    int e = blockIdx.x * 256 + threadIdx.x;
    if (e < E_EDGES) rank[e] = atomicAdd(&counts[ed[e]], 1);
}

// ---------------- hierarchical scan ----------------
__global__ __launch_bounds__(512) void k_scan1(const int* __restrict__ counts,
                                               int* __restrict__ bsum) {
    int i = blockIdx.x * 512 + threadIdx.x;
    int v = (i < N_NODES) ? counts[i] : 0;
    #pragma unroll
    for (int o = 1; o < 64; o <<= 1) v += __shfl_xor(v, o);
    __shared__ int ws[8];
    if ((threadIdx.x & 63) == 0) ws[threadIdx.x >> 6] = v;
    __syncthreads();
    if (threadIdx.x == 0) {
        int s = 0;
        #pragma unroll
        for (int k = 0; k < 8; ++k) s += ws[k];
        bsum[blockIdx.x] = s;
    }
}

__global__ __launch_bounds__(128) void k_scan2(const int* __restrict__ bsum,
                                               int* __restrict__ boff) {
    __shared__ int tmp[128];
    int t = threadIdx.x;
    int v = (t < SCAN_BLOCKS) ? bsum[t] : 0;
    tmp[t] = v;
    __syncthreads();
    for (int o = 1; o < 128; o <<= 1) {
        int u = (t >= o) ? tmp[t - o] : 0;
        __syncthreads();
        tmp[t] += u;
        __syncthreads();
    }
    boff[t] = (t == 0) ? 0 : tmp[t - 1];
}

__global__ __launch_bounds__(512) void k_scan3(const int* __restrict__ counts,
                                               const int* __restrict__ boff,
                                               int* __restrict__ csr_off) {
    int t = threadIdx.x;
    int i = blockIdx.x * 512 + t;
    int v = (i < N_NODES) ? counts[i] : 0;
    int lane = t & 63, w = t >> 6;
    int xs = v;
    #pragma unroll
    for (int o = 1; o < 64; o <<= 1) {
        int u = __shfl_up(xs, o);
        if (lane >= o) xs += u;
    }
    __shared__ int ws[8];
    __shared__ int wo[8];
    if (lane == 63) ws[w] = xs;
    __syncthreads();
    if (t == 0) {
        int s = 0;
        #pragma unroll
        for (int k = 0; k < 8; ++k) { wo[k] = s; s += ws[k]; }
    }
    __syncthreads();
    int excl = xs - v + wo[w] + boff[blockIdx.x];
    if (i < N_NODES) csr_off[i] = excl;
    if (i == N_NODES) csr_off[N_NODES] = E_EDGES;
}

// ---------------- weight prep: transpose + bf16 (+ fused counts zero) -------
__global__ void k_prep(const float* __restrict__ W1, const float* __restrict__ W2,
                       const float* __restrict__ Wfc,
                       bf16_t* __restrict__ W1T, bf16_t* __restrict__ W2T,
                       bf16_t* __restrict__ WpT, int* __restrict__ counts) {
    int id = blockIdx.x * 256 + threadIdx.x;
    if (id < N_NODES) counts[id] = 0;
    if (id < 512 * 128) {
        int c = id >> 7, k = id & 127;
        W1T[id] = (bf16_t)W1[(size_t)k * 512 + c];
        int c2 = id >> 9, k2 = id & 511;
        W2T[id] = (bf16_t)W2[(size_t)k2 * 128 + c2];
        if (id < 128 * 128) {
            int cp = id >> 7, kp = id & 127;
            WpT[id] = (bf16_t)Wfc[(cp >> 4) * 2048 + kp * 16 + (cp & 15)];
        }
    }
}

// ---------------- FUSED: proj (MFMA) blocks || CSR-fill (scatter) blocks ----
// z written HEAD-MAJOR: zbT[h][node][16]; el/er head-major.
__global__ __launch_bounds__(512) void k_fillproj(const float* __restrict__ x,
                                                  const bf16_t* __restrict__ WpT,
                                                  const float* __restrict__ a_l,
                                                  const float* __restrict__ a_r,
                                                  unsigned short* __restrict__ zbT,
                                                  float* __restrict__ elT,
                                                  float* __restrict__ erT,
                                                  const int* __restrict__ es,
                                                  const int* __restrict__ ed,
                                                  const int* __restrict__ rank,
                                                  const int* __restrict__ csr_off,
                                                  int* __restrict__ csr_src) {
    __shared__ char xbA[16384];  // bf16[64][128], row stride 256B, swizzled
    int t = threadIdx.x;

    if (blockIdx.x >= PROJ_BLOCKS) {
        // ---- fill branch: 1024 edges/block, no atomics ----
        int e0 = (blockIdx.x - PROJ_BLOCKS) * 1024 + t;
        #pragma unroll
        for (int k = 0; k < 2; ++k) {
            int e = e0 + k * 512;
            if (e < E_EDGES) {
                int d = ed[e];
                csr_src[csr_off[d] + rank[e]] = es[e];
            }
        }
        return;
    }

    // ---- proj branch ----
    int r0 = blockIdx.x * 64;
    {
        int r = t >> 3, c0 = (t & 7) * 16;
        int gr = r0 + r;
        u16x8 pk0, pk1;
        if (gr < N_NODES) {
            #pragma unroll
            for (int q = 0; q < 2; ++q) {
                float4 a4 = *(const float4*)&x[(size_t)gr * 128 + c0 + q * 8];
                float4 b4 = *(const float4*)&x[(size_t)gr * 128 + c0 + q * 8 + 4];
                u16x8 pk;
                pk[0] = f2b(a4.x); pk[1] = f2b(a4.y); pk[2] = f2b(a4.z); pk[3] = f2b(a4.w);
                pk[4] = f2b(b4.x); pk[5] = f2b(b4.y); pk[6] = f2b(b4.z); pk[7] = f2b(b4.w);
                if (q == 0) pk0 = pk; else pk1 = pk;
            }
        } else {
            #pragma unroll
            for (int i = 0; i < 8; ++i) { pk0[i] = 0; pk1[i] = 0; }
        }
        int base = r * 256 + c0 * 2;
        *(u16x8*)(xbA + (base ^ SWZ(r))) = pk0;
        *(u16x8*)(xbA + ((base + 16) ^ SWZ(r))) = pk1;
    }
    __syncthreads();

    int wv = t >> 6, l = t & 63;
    int lr = l & 15, lg = l >> 4;

    f32x4 acc[4] = {};
    #pragma unroll
    for (int ks = 0; ks < 4; ++ks) {
        bf16x8 b = *(const bf16x8*)(WpT + (wv * 16 + lr) * 128 + ks * 32 + lg * 8);
        #pragma unroll
        for (int mi = 0; mi < 4; ++mi) {
            int row = mi * 16 + lr;
            int off = (row * 256 + ks * 64 + lg * 16) ^ SWZ(row);
            bf16x8 a = *(const bf16x8*)(xbA + off);
            acc[mi] = __builtin_amdgcn_mfma_f32_16x16x32_bf16(a, b, acc[mi], 0, 0, 0);
        }
    }

    float alv = a_l[wv * 16 + lr];
    float arv = a_r[wv * 16 + lr];
    float outL = 0.f, outR = 0.f;
    #pragma unroll
    for (int mi = 0; mi < 4; ++mi) {
        #pragma unroll
        for (int rg = 0; rg < 4; ++rg) {
            int row = mi * 16 + lg * 4 + rg;
            int grr = r0 + row;
            float v = acc[mi][rg];
            if (grr < N_NODES)
                zbT[((size_t)wv * N_NODES + grr) * 16 + lr] = f2b(v);
            float pl = v * alv, pr = v * arv;
            pl += __shfl_xor(pl, 1); pr += __shfl_xor(pr, 1);
            pl += __shfl_xor(pl, 2); pr += __shfl_xor(pr, 2);
            pl += __shfl_xor(pl, 4); pr += __shfl_xor(pr, 4);
            pl += __shfl_xor(pl, 8); pr += __shfl_xor(pr, 8);
            if (lr == mi * 4 + rg) { outL = pl; outR = pr; }
        }
    }
    int myrow = r0 + (lr >> 2) * 16 + lg * 4 + (lr & 3);
    if (myrow < N_NODES) {
        elT[(size_t)wv * N_NODES + myrow] = outL;
        erT[(size_t)wv * N_NODES + myrow] = outR;
    }
}

// ---------------- head-partitioned softmax+aggregate+elu+residual -----------
// head = bid & 7 -> XCD pin; zbT[h] (1.6MB) + elT[h] (200KB) L2-resident.
// Phase A: lane q owns edge q -> ONE exp per edge (no redundancy).
// Phase B: 8-edge sub-chunks; lane q = (edge q>>2, dim-quad q&3) -> 8B gather
// (4 lanes x 8B = full 32B head-slice per edge). 3 shfl_xor fold, q<4 write.
__global__ __launch_bounds__(256) void k_node(const int* __restrict__ csr_off,
                                              const int* __restrict__ csr_src,
                                              const float* __restrict__ elT,
                                              const float* __restrict__ erT,
                                              const unsigned short* __restrict__ zbT,
                                              const float* __restrict__ x,
                                              float* __restrict__ out) {
    int h = blockIdx.x & 7;
    int grp = blockIdx.x >> 3;
    int t = threadIdx.x;
    int hw = t >> 5;             // half-wave = node slot
    int q = t & 31;
    int base = t & 32;           // shuffle base of this half-wave
    const float* elh = elT + (size_t)h * N_NODES;
    const float* erh = erT + (size_t)h * N_NODES;
    const unsigned short* zbh = zbT + (size_t)h * N_NODES * 16;
    int dq4 = (q & 3) * 4;

    for (int it = 0; it < NODE_ITERS; ++it) {
        int n = (grp * NODE_ITERS + it) * 8 + hw;
        int row = csr_off[n];
        int deg = csr_off[n + 1] - row;
        float erv = erh[n];
        float psr = 0.f, a0 = 0.f, a1 = 0.f, a2 = 0.f, a3 = 0.f;

        for (int cc = 0; cc * 32 < deg; ++cc) {
            // phase A: one edge per lane
            int k = cc * 32 + q;
            float p = 0.f;
            int src = 0;
            if (k < deg) {
                src = csr_src[row + k];
                p = __expf(lrelu(elh[src] + erv));
            }
            psr += p;
            // phase B: 4 sub-chunks x 8 edges
            #pragma unroll
            for (int c = 0; c < 4; ++c) {
                if (cc * 32 + c * 8 < deg) {  // uniform across half-wave
                    int eidx = c * 8 + (q >> 2);
                    float ap = __shfl(p, base + eidx);
                    int se = __shfl(src, base + eidx);
                    uint2 u = *(const uint2*)(zbh + (size_t)se * 16 + dq4);
                    a0 += ap * bflo(u.x);
                    a1 += ap * bfhi(u.x);
                    a2 += ap * bflo(u.y);
                    a3 += ap * bfhi(u.y);
                }
            }
        }
        // sum p over all 32 lanes of half-wave
        psr += __shfl_xor(psr, 1);
        psr += __shfl_xor(psr, 2);
        psr += __shfl_xor(psr, 4);
        psr += __shfl_xor(psr, 8);
        psr += __shfl_xor(psr, 16);
        // fold edge groups (bits 2,3,4 of q)
        a0 += __shfl_xor(a0, 4); a0 += __shfl_xor(a0, 8); a0 += __shfl_xor(a0, 16);
        a1 += __shfl_xor(a1, 4); a1 += __shfl_xor(a1, 8); a1 += __shfl_xor(a1, 16);
        a2 += __shfl_xor(a2, 4); a2 += __shfl_xor(a2, 8); a2 += __shfl_xor(a2, 16);
        a3 += __shfl_xor(a3, 4); a3 += __shfl_xor(a3, 8); a3 += __shfl_xor(a3, 16);
        if (q < 4) {
            float inv = 1.f / fmaxf(psr, 1e-9f);
            float4 xv = *(const float4*)&x[(size_t)n * 128 + h * 16 + q * 4];
            float4 hv;
            hv.x = xv.x + elu(a0 * inv);
            hv.y = xv.y + elu(a1 * inv);
            hv.z = xv.z + elu(a2 * inv);
            hv.w = xv.w + elu(a3 * inv);
            *(float4*)&out[(size_t)n * 128 + h * 16 + q * 4] = hv;
        }
    }
}

// ---------------- FFN: weight-stationary persistent kernel + in-reg LN ------
__global__ __launch_bounds__(256, 1) void k_ffn(const bf16_t* __restrict__ W1T,
                                                const float* __restrict__ b1,
                                                const bf16_t* __restrict__ W2T,
                                                const float* __restrict__ b2,
                                                const float* __restrict__ gamma,
                                                const float* __restrict__ beta,
                                                float* __restrict__ out) {
    __shared__ char inA[16384];  // bf16[16 nodes][512 f], row 1024B, swz by node
    int t = threadIdx.x;
    int w = t >> 6, l = t & 63;
    int lr = l & 15, lg = l >> 4;

    bf16x8 w1f[4][8];
    #pragma unroll
    for (int ks = 0; ks < 4; ++ks)
        #pragma unroll
        for (int tf = 0; tf < 8; ++tf)
            w1f[ks][tf] = *(const bf16x8*)(W1T + (size_t)(w * 128 + tf * 16 + lr) * 128 + ks * 32 + lg * 8);
    bf16x8 w2f[16][2];
    #pragma unroll
    for (int ks2 = 0; ks2 < 16; ++ks2)
        #pragma unroll
        for (int tc = 0; tc < 2; ++tc)
            w2f[ks2][tc] = *(const bf16x8*)(W2T + (size_t)(w * 32 + tc * 16 + lr) * 512 + ks2 * 32 + lg * 8);
    float4 b1v[8];
    #pragma unroll
    for (int tf = 0; tf < 8; ++tf)
        b1v[tf] = *(const float4*)&b1[w * 128 + tf * 16 + lg * 4];
    float4 b2v[2];
    #pragma unroll
    for (int tc = 0; tc < 2; ++tc)
        b2v[tc] = *(const float4*)&b2[w * 32 + tc * 16 + lg * 4];

    int tile = blockIdx.x;
    while (tile < NTILES) {
        const float* hbase = out + (size_t)(tile * 16 + lr) * 128;
        float4 h4[2];
        #pragma unroll
        for (int tc = 0; tc < 2; ++tc)
            h4[tc] = *(const float4*)(hbase + w * 32 + tc * 16 + lg * 4);

        // h fragments + in-register LN
        float hvv[4][8];
        float sm = 0.f, sq = 0.f;
        #pragma unroll
        for (int ks = 0; ks < 4; ++ks) {
            float4 A = *(const float4*)(hbase + ks * 32 + lg * 8);
            float4 B = *(const float4*)(hbase + ks * 32 + lg * 8 + 4);
            hvv[ks][0] = A.x; hvv[ks][1] = A.y; hvv[ks][2] = A.z; hvv[ks][3] = A.w;
            hvv[ks][4] = B.x; hvv[ks][5] = B.y; hvv[ks][6] = B.z; hvv[ks][7] = B.w;
            #pragma unroll
            for (int j = 0; j < 8; ++j) { sm += hvv[ks][j]; sq += hvv[ks][j] * hvv[ks][j]; }
        }
        sm += __shfl_xor(sm, 16); sq += __shfl_xor(sq, 16);
        sm += __shfl_xor(sm, 32); sq += __shfl_xor(sq, 32);
        float mu = sm * (1.f / 128.f);
        float rs = rsqrtf(sq * (1.f / 128.f) - mu * mu + 1e-5f);
        bf16x8 cur[4];
        #pragma unroll
        for (int ks = 0; ks < 4; ++ks) {
            float4 g0 = *(const float4*)&gamma[ks * 32 + lg * 8];
            float4 g1 = *(const float4*)&gamma[ks * 32 + lg * 8 + 4];
            float4 be0 = *(const float4*)&beta[ks * 32 + lg * 8];
            float4 be1 = *(const float4*)&beta[ks * 32 + lg * 8 + 4];
            float ga[8] = {g0.x, g0.y, g0.z, g0.w, g1.x, g1.y, g1.z, g1.w};
            float ba[8] = {be0.x, be0.y, be0.z, be0.w, be1.x, be1.y, be1.z, be1.w};
            u16x8 pk;
            #pragma unroll
            for (int j = 0; j < 8; ++j)
                pk[j] = f2b((hvv[ks][j] - mu) * rs * ga[j] + ba[j]);
            cur[ks] = __builtin_bit_cast(bf16x8, pk);
        }

        f32x4 p[8] = {};
        #pragma unroll
        for (int ks = 0; ks < 4; ++ks)
            #pragma unroll
            for (int tf = 0; tf < 8; ++tf)
                p[tf] = __builtin_amdgcn_mfma_f32_16x16x32_bf16(w1f[ks][tf], cur[ks], p[tf], 0, 0, 0);

        #pragma unroll
        for (int tf = 0; tf < 8; ++tf) {
            float4 bb = b1v[tf];
            ushort4 pk;
            float v0 = p[tf][0] + bb.x; pk.x = f2b(v0 > 0.f ? v0 : 0.f);
            float v1 = p[tf][1] + bb.y; pk.y = f2b(v1 > 0.f ? v1 : 0.f);
            float v2 = p[tf][2] + bb.z; pk.z = f2b(v2 > 0.f ? v2 : 0.f);
            float v3 = p[tf][3] + bb.w; pk.w = f2b(v3 > 0.f ? v3 : 0.f);
            *(ushort4*)(inA + ((lr * 1024 + w * 256 + tf * 32 + lg * 8) ^ SWZ(lr))) = pk;
        }
        __syncthreads();

        f32x4 Q[2] = {};
        #pragma unroll
        for (int ks2 = 0; ks2 < 16; ++ks2) {
            bf16x8 bfr = *(const bf16x8*)(inA + ((lr * 1024 + ks2 * 64 + lg * 16) ^ SWZ(lr)));
            #pragma unroll
            for (int tc = 0; tc < 2; ++tc)
                Q[tc] = __builtin_amdgcn_mfma_f32_16x16x32_bf16(w2f[ks2][tc], bfr, Q[tc], 0, 0, 0);
        }

        #pragma unroll
        for (int tc = 0; tc < 2; ++tc) {
            float4 o4;
            o4.x = Q[tc][0] + b2v[tc].x + h4[tc].x;
            o4.y = Q[tc][1] + b2v[tc].y + h4[tc].y;
            o4.z = Q[tc][2] + b2v[tc].z + h4[tc].z;
            o4.w = Q[tc][3] + b2v[tc].w + h4[tc].w;
            *(float4*)(out + (size_t)(tile * 16 + lr) * 128 + w * 32 + tc * 16 + lg * 4) = o4;
        }
        __syncthreads();
        tile += FFN_GRID;
    }
}

extern "C" void kernel_launch(void* const* d_in, const int* in_sizes, int n_in,
                              void* d_out, int out_size, void* d_ws, size_t ws_size,
                              hipStream_t stream) {
    const float* x     = (const float*)d_in[0];
    const float* Wfc   = (const float*)d_in[1];
    const float* a_l   = (const float*)d_in[2];
    const float* a_r   = (const float*)d_in[3];
    const float* gamma = (const float*)d_in[4];
    const float* beta  = (const float*)d_in[5];
    const float* W1    = (const float*)d_in[6];
    const float* b1    = (const float*)d_in[7];
    const float* W2    = (const float*)d_in[8];
    const float* b2    = (const float*)d_in[9];
    const int*   es    = (const int*)d_in[10];
    const int*   ed    = (const int*)d_in[11];
    float* out = (float*)d_out;

    bf16_t* W1T = (bf16_t*)d_ws;                      // 512*128
    bf16_t* W2T = W1T + 512 * 128;                    // 128*512
    bf16_t* WpT = W2T + 128 * 512;                    // 128*128
    unsigned short* zbT = (unsigned short*)(WpT + 128 * 128);  // 8*N*16 bf16 (head-major)
    float* elT = (float*)(zbT + (size_t)N_NODES * 128);  // 8*N (head-major)
    float* erT = elT + (size_t)8 * N_NODES;             // 8*N
    int* counts  = (int*)(erT + (size_t)8 * N_NODES);   // N
    int* csr_off = counts + N_NODES;                  // N+1
    int* csr_src = csr_off + N_NODES + 1;             // E
    int* rank    = csr_src + E_EDGES;                 // E
    int* bsum    = rank + E_EDGES;                    // 128
    int* boff    = bsum + 128;                        // 128

    k_prep<<<dim3(256), dim3(256), 0, stream>>>(W1, W2, Wfc, W1T, W2T, WpT, counts);
    k_count<<<dim3((E_EDGES + 255) / 256), dim3(256), 0, stream>>>(ed, counts, rank);
    k_scan1<<<dim3(SCAN_BLOCKS), dim3(512), 0, stream>>>(counts, bsum);
    k_scan2<<<dim3(1), dim3(128), 0, stream>>>(bsum, boff);
    k_scan3<<<dim3(SCAN_BLOCKS), dim3(512), 0, stream>>>(counts, boff, csr_off);
    k_fillproj<<<dim3(PROJ_BLOCKS + FILL_BLOCKS), dim3(512), 0, stream>>>(
        x, WpT, a_l, a_r, zbT, elT, erT, es, ed, rank, csr_off, csr_src);
    k_node<<<dim3(KNODE_GRID), dim3(256), 0, stream>>>(csr_off, csr_src, elT, erT, zbT, x, out);
    k_ffn<<<dim3(FFN_GRID), dim3(256), 0, stream>>>(W1T, b1, W2T, b2, gamma, beta, out);
}

// Round 18
// 173.502 us; speedup vs baseline: 1.4511x; 1.1877x over previous
//
#include <hip/hip_runtime.h>
#include <math.h>

#define N_NODES 50000
#define E_EDGES 800000
#define D_DIM   128
#define H_HEADS 8
#define DH_DIM  16
#define DFF     512

#define SCAN_BLOCKS 98  // 98*512 = 50176 >= N_NODES+1
#define FFN_GRID 256
#define NTILES 3125     // 50000 / 16 exactly
#define PROJ_BLOCKS 782 // ceil(50000/64)
#define FILL_BLOCKS 782 // ceil(800000/1024)

typedef __bf16 bf16_t;
typedef bf16_t bf16x8 __attribute__((ext_vector_type(8)));
typedef float f32x4 __attribute__((ext_vector_type(4)));
typedef unsigned short u16x8 __attribute__((ext_vector_type(8)));

#define SWZ(r) (((r) & 7) << 4)

__device__ __forceinline__ float lrelu(float v) { return v > 0.f ? v : 0.01f * v; }
__device__ __forceinline__ float elu(float v) { return v > 0.f ? v : __expf(v) - 1.f; }
__device__ __forceinline__ unsigned short f2b(float f) {
    unsigned u = __float_as_uint(f);
    unsigned r = (u + 0x7FFFu + ((u >> 16) & 1u)) >> 16;
    return (unsigned short)r;
}

// ---------------- count in-degree + capture rank ----------------
__global__ void k_count(const int* __restrict__ ed, int* __restrict__ counts,
                        int* __restrict__ rank) {
    int e = blockIdx.x * 256 + threadIdx.x;
    if (e < E_EDGES) rank[e] = atomicAdd(&counts[ed[e]], 1);
}

// ---------------- hierarchical scan ----------------
__global__ __launch_bounds__(512) void k_scan1(const int* __restrict__ counts,
                                               int* __restrict__ bsum) {
    int i = blockIdx.x * 512 + threadIdx.x;
    int v = (i < N_NODES) ? counts[i] : 0;
    #pragma unroll
    for (int o = 1; o < 64; o <<= 1) v += __shfl_xor(v, o);
    __shared__ int ws[8];
    if ((threadIdx.x & 63) == 0) ws[threadIdx.x >> 6] = v;
    __syncthreads();
    if (threadIdx.x == 0) {
        int s = 0;
        #pragma unroll
        for (int k = 0; k < 8; ++k) s += ws[k];
        bsum[blockIdx.x] = s;
    }
}

__global__ __launch_bounds__(128) void k_scan2(const int* __restrict__ bsum,
                                               int* __restrict__ boff) {
    __shared__ int tmp[128];
    int t = threadIdx.x;
    int v = (t < SCAN_BLOCKS) ? bsum[t] : 0;
    tmp[t] = v;
    __syncthreads();
    for (int o = 1; o < 128; o <<= 1) {
        int u = (t >= o) ? tmp[t - o] : 0;
        __syncthreads();
        tmp[t] += u;
        __syncthreads();
    }
    boff[t] = (t == 0) ? 0 : tmp[t - 1];
}

__global__ __launch_bounds__(512) void k_scan3(const int* __restrict__ counts,
                                               const int* __restrict__ boff,
                                               int* __restrict__ csr_off) {
    int t = threadIdx.x;
    int i = blockIdx.x * 512 + t;
    int v = (i < N_NODES) ? counts[i] : 0;
    int lane = t & 63, w = t >> 6;
    int xs = v;
    #pragma unroll
    for (int o = 1; o < 64; o <<= 1) {
        int u = __shfl_up(xs, o);
        if (lane >= o) xs += u;
    }
    __shared__ int ws[8];
    __shared__ int wo[8];
    if (lane == 63) ws[w] = xs;
    __syncthreads();
    if (t == 0) {
        int s = 0;
        #pragma unroll
        for (int k = 0; k < 8; ++k) { wo[k] = s; s += ws[k]; }
    }
    __syncthreads();
    int excl = xs - v + wo[w] + boff[blockIdx.x];
    if (i < N_NODES) csr_off[i] = excl;
    if (i == N_NODES) csr_off[N_NODES] = E_EDGES;
}

// ---------------- weight prep: transpose + bf16 (+ fused counts zero) -------
__global__ void k_prep(const float* __restrict__ W1, const float* __restrict__ W2,
                       const float* __restrict__ Wfc,
                       bf16_t* __restrict__ W1T, bf16_t* __restrict__ W2T,
                       bf16_t* __restrict__ WpT, int* __restrict__ counts) {
    int id = blockIdx.x * 256 + threadIdx.x;
    if (id < N_NODES) counts[id] = 0;
    if (id < 512 * 128) {
        int c = id >> 7, k = id & 127;
        W1T[id] = (bf16_t)W1[(size_t)k * 512 + c];
        int c2 = id >> 9, k2 = id & 511;
        W2T[id] = (bf16_t)W2[(size_t)k2 * 128 + c2];
        if (id < 128 * 128) {
            int cp = id >> 7, kp = id & 127;
            WpT[id] = (bf16_t)Wfc[(cp >> 4) * 2048 + kp * 16 + (cp & 15)];
        }
    }
}

// ---------------- FUSED: proj (MFMA) blocks || CSR-fill (scatter) blocks ----
// zb/el/er node-major (R14 layout: one csr pass serves all 8 heads in k_node).
__global__ __launch_bounds__(512) void k_fillproj(const float* __restrict__ x,
                                                  const bf16_t* __restrict__ WpT,
                                                  const float* __restrict__ a_l,
                                                  const float* __restrict__ a_r,
                                                  unsigned short* __restrict__ zb,
                                                  float* __restrict__ el,
                                                  float* __restrict__ er,
                                                  const int* __restrict__ es,
                                                  const int* __restrict__ ed,
                                                  const int* __restrict__ rank,
                                                  const int* __restrict__ csr_off,
                                                  int* __restrict__ csr_src) {
    __shared__ char xbA[16384];  // bf16[64][128], row stride 256B, swizzled
    int t = threadIdx.x;

    if (blockIdx.x >= PROJ_BLOCKS) {
        // ---- fill branch: 1024 edges/block, no atomics ----
        int e0 = (blockIdx.x - PROJ_BLOCKS) * 1024 + t;
        #pragma unroll
        for (int k = 0; k < 2; ++k) {
            int e = e0 + k * 512;
            if (e < E_EDGES) {
                int d = ed[e];
                csr_src[csr_off[d] + rank[e]] = es[e];
            }
        }
        return;
    }

    // ---- proj branch ----
    int r0 = blockIdx.x * 64;
    {
        int r = t >> 3, c0 = (t & 7) * 16;
        int gr = r0 + r;
        u16x8 pk0, pk1;
        if (gr < N_NODES) {
            #pragma unroll
            for (int q = 0; q < 2; ++q) {
                float4 a4 = *(const float4*)&x[(size_t)gr * 128 + c0 + q * 8];
                float4 b4 = *(const float4*)&x[(size_t)gr * 128 + c0 + q * 8 + 4];
                u16x8 pk;
                pk[0] = f2b(a4.x); pk[1] = f2b(a4.y); pk[2] = f2b(a4.z); pk[3] = f2b(a4.w);
                pk[4] = f2b(b4.x); pk[5] = f2b(b4.y); pk[6] = f2b(b4.z); pk[7] = f2b(b4.w);
                if (q == 0) pk0 = pk; else pk1 = pk;
            }
        } else {
            #pragma unroll
            for (int i = 0; i < 8; ++i) { pk0[i] = 0; pk1[i] = 0; }
        }
        int base = r * 256 + c0 * 2;
        *(u16x8*)(xbA + (base ^ SWZ(r))) = pk0;
        *(u16x8*)(xbA + ((base + 16) ^ SWZ(r))) = pk1;
    }
    __syncthreads();

    int wv = t >> 6, l = t & 63;
    int lr = l & 15, lg = l >> 4;

    f32x4 acc[4] = {};
    #pragma unroll
    for (int ks = 0; ks < 4; ++ks) {
        bf16x8 b = *(const bf16x8*)(WpT + (wv * 16 + lr) * 128 + ks * 32 + lg * 8);
        #pragma unroll
        for (int mi = 0; mi < 4; ++mi) {
            int row = mi * 16 + lr;
            int off = (row * 256 + ks * 64 + lg * 16) ^ SWZ(row);
            bf16x8 a = *(const bf16x8*)(xbA + off);
            acc[mi] = __builtin_amdgcn_mfma_f32_16x16x32_bf16(a, b, acc[mi], 0, 0, 0);
        }
    }

    float alv = a_l[wv * 16 + lr];
    float arv = a_r[wv * 16 + lr];
    float outL = 0.f, outR = 0.f;
    #pragma unroll
    for (int mi = 0; mi < 4; ++mi) {
        #pragma unroll
        for (int rg = 0; rg < 4; ++rg) {
            int row = mi * 16 + lg * 4 + rg;
            int grr = r0 + row;
            float v = acc[mi][rg];
            if (grr < N_NODES) zb[(size_t)grr * 128 + wv * 16 + lr] = f2b(v);
            float pl = v * alv, pr = v * arv;
            pl += __shfl_xor(pl, 1); pr += __shfl_xor(pr, 1);
            pl += __shfl_xor(pl, 2); pr += __shfl_xor(pr, 2);
            pl += __shfl_xor(pl, 4); pr += __shfl_xor(pr, 4);
            pl += __shfl_xor(pl, 8); pr += __shfl_xor(pr, 8);
            if (lr == mi * 4 + rg) { outL = pl; outR = pr; }
        }
    }
    int myrow = r0 + (lr >> 2) * 16 + lg * 4 + (lr & 3);
    if (myrow < N_NODES) {
        el[myrow * 8 + wv] = outL;
        er[myrow * 8 + wv] = outR;
    }
}

// ---------------- fused softmax + aggregate + elu + residual ----------------
// R14 structure (best measured: 47us): TWO nodes per wave, single pass,
// node-major zb. Lane q (0..31): head h=q>>2 owns dims 4q..4q+3, slot s=q&3.
// One csr pass serves all 8 heads. LN now lives in k_ffn.
__global__ __launch_bounds__(256) void k_node(const int* __restrict__ csr_off,
                                              const int* __restrict__ csr_src,
                                              const float* __restrict__ el,
                                              const float* __restrict__ er,
                                              const unsigned short* __restrict__ zb,
                                              const float* __restrict__ x,
                                              float* __restrict__ out) {
    int n = blockIdx.x * 8 + (threadIdx.x >> 5);
    int lane = threadIdx.x & 63;
    int q = lane & 31;
    int base = lane & 32;       // shuffle base of this half-wave
    int h = q >> 2, s = q & 3;
    int row = csr_off[n];
    int deg = csr_off[n + 1] - row;
    float4 xv = *(const float4*)&x[(size_t)n * 128 + q * 4];
    float erv = er[n * 8 + h];
    int nch = (deg + 3) >> 2;

    float ps = 0.f;
    float ac0 = 0.f, ac1 = 0.f, ac2 = 0.f, ac3 = 0.f;
    const unsigned short* zbl = zb + q * 4;
    #pragma unroll
    for (int c = 0; c < 8; ++c) {
        if (c * 4 < deg) {  // uniform across half-wave
            int k = c * 4 + s;
            int kk = min(k, deg - 1);          // branch-free clamp
            int src = csr_src[row + kk];
            float e = lrelu(el[src * 8 + h] + erv);
            float p = (k < deg) ? __expf(e) : 0.f;
            ps += p;
            float a[4];
            int se[4];
            #pragma unroll
            for (int tt = 0; tt < 4; ++tt) {
                a[tt] = __shfl(p, base + h * 4 + tt);
                se[tt] = __shfl(src, base + tt);
            }
            uint2 u[4];
            #pragma unroll
            for (int tt = 0; tt < 4; ++tt)
                u[tt] = *(const uint2*)(zbl + (size_t)se[tt] * 128);
            #pragma unroll
            for (int tt = 0; tt < 4; ++tt) {
                ac0 += a[tt] * __uint_as_float(u[tt].x << 16);
                ac1 += a[tt] * __uint_as_float(u[tt].x & 0xFFFF0000u);
                ac2 += a[tt] * __uint_as_float(u[tt].y << 16);
                ac3 += a[tt] * __uint_as_float(u[tt].y & 0xFFFF0000u);
            }
        }
    }
    for (int c = 8; c < nch; ++c) {  // rare: deg > 32
        int k = c * 4 + s;
        int kk = min(k, deg - 1);
        int src = csr_src[row + kk];
        float e = lrelu(el[src * 8 + h] + erv);
        float p = (k < deg) ? __expf(e) : 0.f;
        ps += p;
        float a[4];
        int se[4];
        #pragma unroll
        for (int tt = 0; tt < 4; ++tt) {
            a[tt] = __shfl(p, base + h * 4 + tt);
            se[tt] = __shfl(src, base + tt);
        }
        uint2 u[4];
        #pragma unroll
        for (int tt = 0; tt < 4; ++tt)
            u[tt] = *(const uint2*)(zbl + (size_t)se[tt] * 128);
        #pragma unroll
        for (int tt = 0; tt < 4; ++tt) {
            ac0 += a[tt] * __uint_as_float(u[tt].x << 16);
            ac1 += a[tt] * __uint_as_float(u[tt].x & 0xFFFF0000u);
            ac2 += a[tt] * __uint_as_float(u[tt].y << 16);
            ac3 += a[tt] * __uint_as_float(u[tt].y & 0xFFFF0000u);
        }
    }
    // per-head sum over the 4 edge slots (bits 0,1 of q)
    ps += __shfl_xor(ps, 1);
    ps += __shfl_xor(ps, 2);
    float inv = 1.f / fmaxf(ps, 1e-9f);
    float4 hv;
    hv.x = xv.x + elu(ac0 * inv);
    hv.y = xv.y + elu(ac1 * inv);
    hv.z = xv.z + elu(ac2 * inv);
    hv.w = xv.w + elu(ac3 * inv);
    *(float4*)&out[(size_t)n * 128 + q * 4] = hv;
}

// ---------------- FFN: weight-stationary persistent kernel + in-reg LN ------
__global__ __launch_bounds__(256, 1) void k_ffn(const bf16_t* __restrict__ W1T,
                                                const float* __restrict__ b1,
                                                const bf16_t* __restrict__ W2T,
                                                const float* __restrict__ b2,
                                                const float* __restrict__ gamma,
                                                const float* __restrict__ beta,
                                                float* __restrict__ out) {
    __shared__ char inA[16384];  // bf16[16 nodes][512 f], row 1024B, swz by node
    int t = threadIdx.x;
    int w = t >> 6, l = t & 63;
    int lr = l & 15, lg = l >> 4;

    bf16x8 w1f[4][8];
    #pragma unroll
    for (int ks = 0; ks < 4; ++ks)
        #pragma unroll
        for (int tf = 0; tf < 8; ++tf)
            w1f[ks][tf] = *(const bf16x8*)(W1T + (size_t)(w * 128 + tf * 16 + lr) * 128 + ks * 32 + lg * 8);
    bf16x8 w2f[16][2];
    #pragma unroll
    for (int ks2 = 0; ks2 < 16; ++ks2)
        #pragma unroll
        for (int tc = 0; tc < 2; ++tc)
            w2f[ks2][tc] = *(const bf16x8*)(W2T + (size_t)(w * 32 + tc * 16 + lr) * 512 + ks2 * 32 + lg * 8);
    float4 b1v[8];
    #pragma unroll
    for (int tf = 0; tf < 8; ++tf)
        b1v[tf] = *(const float4*)&b1[w * 128 + tf * 16 + lg * 4];
    float4 b2v[2];
    #pragma unroll
    for (int tc = 0; tc < 2; ++tc)
        b2v[tc] = *(const float4*)&b2[w * 32 + tc * 16 + lg * 4];

    int tile = blockIdx.x;
    while (tile < NTILES) {
        const float* hbase = out + (size_t)(tile * 16 + lr) * 128;
        float4 h4[2];
        #pragma unroll
        for (int tc = 0; tc < 2; ++tc)
            h4[tc] = *(const float4*)(hbase + w * 32 + tc * 16 + lg * 4);

        // h fragments + in-register LN
        float hvv[4][8];
        float sm = 0.f, sq = 0.f;
        #pragma unroll
        for (int ks = 0; ks < 4; ++ks) {
            float4 A = *(const float4*)(hbase + ks * 32 + lg * 8);
            float4 B = *(const float4*)(hbase + ks * 32 + lg * 8 + 4);
            hvv[ks][0] = A.x; hvv[ks][1] = A.y; hvv[ks][2] = A.z; hvv[ks][3] = A.w;
            hvv[ks][4] = B.x; hvv[ks][5] = B.y; hvv[ks][6] = B.z; hvv[ks][7] = B.w;
            #pragma unroll
            for (int j = 0; j < 8; ++j) { sm += hvv[ks][j]; sq += hvv[ks][j] * hvv[ks][j]; }
        }
        sm += __shfl_xor(sm, 16); sq += __shfl_xor(sq, 16);
        sm += __shfl_xor(sm, 32); sq += __shfl_xor(sq, 32);
        float mu = sm * (1.f / 128.f);
        float rs = rsqrtf(sq * (1.f / 128.f) - mu * mu + 1e-5f);
        bf16x8 cur[4];
        #pragma unroll
        for (int ks = 0; ks < 4; ++ks) {
            float4 g0 = *(const float4*)&gamma[ks * 32 + lg * 8];
            float4 g1 = *(const float4*)&gamma[ks * 32 + lg * 8 + 4];
            float4 be0 = *(const float4*)&beta[ks * 32 + lg * 8];
            float4 be1 = *(const float4*)&beta[ks * 32 + lg * 8 + 4];
            float ga[8] = {g0.x, g0.y, g0.z, g0.w, g1.x, g1.y, g1.z, g1.w};
            float ba[8] = {be0.x, be0.y, be0.z, be0.w, be1.x, be1.y, be1.z, be1.w};
            u16x8 pk;
            #pragma unroll
            for (int j = 0; j < 8; ++j)
                pk[j] = f2b((hvv[ks][j] - mu) * rs * ga[j] + ba[j]);
            cur[ks] = __builtin_bit_cast(bf16x8, pk);
        }

        f32x4 p[8] = {};
        #pragma unroll
        for (int ks = 0; ks < 4; ++ks)
            #pragma unroll
            for (int tf = 0; tf < 8; ++tf)
                p[tf] = __builtin_amdgcn_mfma_f32_16x16x32_bf16(w1f[ks][tf], cur[ks], p[tf], 0, 0, 0);

        #pragma unroll
        for (int tf = 0; tf < 8; ++tf) {
            float4 bb = b1v[tf];
            ushort4 pk;
            float v0 = p[tf][0] + bb.x; pk.x = f2b(v0 > 0.f ? v0 : 0.f);
            float v1 = p[tf][1] + bb.y; pk.y = f2b(v1 > 0.f ? v1 : 0.f);
            float v2 = p[tf][2] + bb.z; pk.z = f2b(v2 > 0.f ? v2 : 0.f);
            float v3 = p[tf][3] + bb.w; pk.w = f2b(v3 > 0.f ? v3 : 0.f);
            *(ushort4*)(inA + ((lr * 1024 + w * 256 + tf * 32 + lg * 8) ^ SWZ(lr))) = pk;
        }
        __syncthreads();

        f32x4 Q[2] = {};
        #pragma unroll
        for (int ks2 = 0; ks2 < 16; ++ks2) {
            bf16x8 bfr = *(const bf16x8*)(inA + ((lr * 1024 + ks2 * 64 + lg * 16) ^ SWZ(lr)));
            #pragma unroll
            for (int tc = 0; tc < 2; ++tc)
                Q[tc] = __builtin_amdgcn_mfma_f32_16x16x32_bf16(w2f[ks2][tc], bfr, Q[tc], 0, 0, 0);
        }

        #pragma unroll
        for (int tc = 0; tc < 2; ++tc) {
            float4 o4;
            o4.x = Q[tc][0] + b2v[tc].x + h4[tc].x;
            o4.y = Q[tc][1] + b2v[tc].y + h4[tc].y;
            o4.z = Q[tc][2] + b2v[tc].z + h4[tc].z;
            o4.w = Q[tc][3] + b2v[tc].w + h4[tc].w;
            *(float4*)(out + (size_t)(tile * 16 + lr) * 128 + w * 32 + tc * 16 + lg * 4) = o4;
        }
        __syncthreads();
        tile += FFN_GRID;
    }
}

extern "C" void kernel_launch(void* const* d_in, const int* in_sizes, int n_in,
                              void* d_out, int out_size, void* d_ws, size_t ws_size,
                              hipStream_t stream) {
    const float* x     = (const float*)d_in[0];
    const float* Wfc   = (const float*)d_in[1];
    const float* a_l   = (const float*)d_in[2];
    const float* a_r   = (const float*)d_in[3];
    const float* gamma = (const float*)d_in[4];
    const float* beta  = (const float*)d_in[5];
    const float* W1    = (const float*)d_in[6];
    const float* b1    = (const float*)d_in[7];
    const float* W2    = (const float*)d_in[8];
    const float* b2    = (const float*)d_in[9];
    const int*   es    = (const int*)d_in[10];
    const int*   ed    = (const int*)d_in[11];
    float* out = (float*)d_out;

    bf16_t* W1T = (bf16_t*)d_ws;                      // 512*128
    bf16_t* W2T = W1T + 512 * 128;                    // 128*512
    bf16_t* WpT = W2T + 128 * 512;                    // 128*128
    unsigned short* zb = (unsigned short*)(WpT + 128 * 128);  // N*128 bf16 (node-major)
    float* el = (float*)(zb + (size_t)N_NODES * 128); // N*8 (node-major)
    float* er = el + N_NODES * 8;                     // N*8
    int* counts  = (int*)(er + N_NODES * 8);          // N
    int* csr_off = counts + N_NODES;                  // N+1
    int* csr_src = csr_off + N_NODES + 1;             // E
    int* rank    = csr_src + E_EDGES;                 // E
    int* bsum    = rank + E_EDGES;                    // 128
    int* boff    = bsum + 128;                        // 128

    k_prep<<<dim3(256), dim3(256), 0, stream>>>(W1, W2, Wfc, W1T, W2T, WpT, counts);
    k_count<<<dim3((E_EDGES + 255) / 256), dim3(256), 0, stream>>>(ed, counts, rank);
    k_scan1<<<dim3(SCAN_BLOCKS), dim3(512), 0, stream>>>(counts, bsum);
    k_scan2<<<dim3(1), dim3(128), 0, stream>>>(bsum, boff);
    k_scan3<<<dim3(SCAN_BLOCKS), dim3(512), 0, stream>>>(counts, boff, csr_off);
    k_fillproj<<<dim3(PROJ_BLOCKS + FILL_BLOCKS), dim3(512), 0, stream>>>(
        x, WpT, a_l, a_r, zb, el, er, es, ed, rank, csr_off, csr_src);
    k_node<<<dim3(N_NODES / 8), dim3(256), 0, stream>>>(csr_off, csr_src, el, er, zb, x, out);
    k_ffn<<<dim3(FFN_GRID), dim3(256), 0, stream>>>(W1T, b1, W2T, b2, gamma, beta, out);
}

// Round 19
// 167.641 us; speedup vs baseline: 1.5018x; 1.0350x over previous
//
#include <hip/hip_runtime.h>
#include <math.h>

#define N_NODES 50000
#define E_EDGES 800000
#define D_DIM   128
#define H_HEADS 8
#define DH_DIM  16
#define DFF     512

#define SCAN_BLOCKS 98  // 98*512 = 50176 >= N_NODES+1
#define FFN_GRID 256
#define NTILES 3125     // 50000 / 16 exactly
#define PROJ_BLOCKS 782 // ceil(50000/64)
#define FILL_BLOCKS 782 // ceil(800000/1024)

typedef __bf16 bf16_t;
typedef bf16_t bf16x8 __attribute__((ext_vector_type(8)));
typedef float f32x4 __attribute__((ext_vector_type(4)));
typedef unsigned short u16x8 __attribute__((ext_vector_type(8)));

#define SWZ(r) (((r) & 7) << 4)

__device__ __forceinline__ float lrelu(float v) { return v > 0.f ? v : 0.01f * v; }
__device__ __forceinline__ float elu(float v) { return v > 0.f ? v : __expf(v) - 1.f; }
__device__ __forceinline__ unsigned short f2b(float f) {
    unsigned u = __float_as_uint(f);
    unsigned r = (u + 0x7FFFu + ((u >> 16) & 1u)) >> 16;
    return (unsigned short)r;
}

// ---------------- count in-degree + capture rank ----------------
__global__ void k_count(const int* __restrict__ ed, int* __restrict__ counts,
                        int* __restrict__ rank) {
    int e = blockIdx.x * 256 + threadIdx.x;
    if (e < E_EDGES) rank[e] = atomicAdd(&counts[ed[e]], 1);
}

// ---------------- hierarchical scan ----------------
__global__ __launch_bounds__(512) void k_scan1(const int* __restrict__ counts,
                                               int* __restrict__ bsum) {
    int i = blockIdx.x * 512 + threadIdx.x;
    int v = (i < N_NODES) ? counts[i] : 0;
    #pragma unroll
    for (int o = 1; o < 64; o <<= 1) v += __shfl_xor(v, o);
    __shared__ int ws[8];
    if ((threadIdx.x & 63) == 0) ws[threadIdx.x >> 6] = v;
    __syncthreads();
    if (threadIdx.x == 0) {
        int s = 0;
        #pragma unroll
        for (int k = 0; k < 8; ++k) s += ws[k];
        bsum[blockIdx.x] = s;
    }
}

__global__ __launch_bounds__(128) void k_scan2(const int* __restrict__ bsum,
                                               int* __restrict__ boff) {
    __shared__ int tmp[128];
    int t = threadIdx.x;
    int v = (t < SCAN_BLOCKS) ? bsum[t] : 0;
    tmp[t] = v;
    __syncthreads();
    for (int o = 1; o < 128; o <<= 1) {
        int u = (t >= o) ? tmp[t - o] : 0;
        __syncthreads();
        tmp[t] += u;
        __syncthreads();
    }
    boff[t] = (t == 0) ? 0 : tmp[t - 1];
}

__global__ __launch_bounds__(512) void k_scan3(const int* __restrict__ counts,
                                               const int* __restrict__ boff,
                                               int* __restrict__ csr_off) {
    int t = threadIdx.x;
    int i = blockIdx.x * 512 + t;
    int v = (i < N_NODES) ? counts[i] : 0;
    int lane = t & 63, w = t >> 6;
    int xs = v;
    #pragma unroll
    for (int o = 1; o < 64; o <<= 1) {
        int u = __shfl_up(xs, o);
        if (lane >= o) xs += u;
    }
    __shared__ int ws[8];
    __shared__ int wo[8];
    if (lane == 63) ws[w] = xs;
    __syncthreads();
    if (t == 0) {
        int s = 0;
        #pragma unroll
        for (int k = 0; k < 8; ++k) { wo[k] = s; s += ws[k]; }
    }
    __syncthreads();
    int excl = xs - v + wo[w] + boff[blockIdx.x];
    if (i < N_NODES) csr_off[i] = excl;
    if (i == N_NODES) csr_off[N_NODES] = E_EDGES;
}

// ---------------- weight prep: transpose + bf16 (+ fused counts zero) -------
__global__ void k_prep(const float* __restrict__ W1, const float* __restrict__ W2,
                       const float* __restrict__ Wfc,
                       bf16_t* __restrict__ W1T, bf16_t* __restrict__ W2T,
                       bf16_t* __restrict__ WpT, int* __restrict__ counts) {
    int id = blockIdx.x * 256 + threadIdx.x;
    if (id < N_NODES) counts[id] = 0;
    if (id < 512 * 128) {
        int c = id >> 7, k = id & 127;
        W1T[id] = (bf16_t)W1[(size_t)k * 512 + c];
        int c2 = id >> 9, k2 = id & 511;
        W2T[id] = (bf16_t)W2[(size_t)k2 * 128 + c2];
        if (id < 128 * 128) {
            int cp = id >> 7, kp = id & 127;
            WpT[id] = (bf16_t)Wfc[(cp >> 4) * 2048 + kp * 16 + (cp & 15)];
        }
    }
}

// ---------------- FUSED: proj (MFMA) blocks || CSR-fill (scatter) blocks ----
__global__ __launch_bounds__(512) void k_fillproj(const float* __restrict__ x,
                                                  const bf16_t* __restrict__ WpT,
                                                  const float* __restrict__ a_l,
                                                  const float* __restrict__ a_r,
                                                  unsigned short* __restrict__ zb,
                                                  float* __restrict__ el,
                                                  float* __restrict__ er,
                                                  const int* __restrict__ es,
                                                  const int* __restrict__ ed,
                                                  const int* __restrict__ rank,
                                                  const int* __restrict__ csr_off,
                                                  int* __restrict__ csr_src) {
    __shared__ char xbA[16384];  // bf16[64][128], row stride 256B, swizzled
    int t = threadIdx.x;

    if (blockIdx.x >= PROJ_BLOCKS) {
        // ---- fill branch: 1024 edges/block, no atomics ----
        int e0 = (blockIdx.x - PROJ_BLOCKS) * 1024 + t;
        #pragma unroll
        for (int k = 0; k < 2; ++k) {
            int e = e0 + k * 512;
            if (e < E_EDGES) {
                int d = ed[e];
                csr_src[csr_off[d] + rank[e]] = es[e];
            }
        }
        return;
    }

    // ---- proj branch ----
    int r0 = blockIdx.x * 64;
    {
        int r = t >> 3, c0 = (t & 7) * 16;
        int gr = r0 + r;
        u16x8 pk0, pk1;
        if (gr < N_NODES) {
            #pragma unroll
            for (int q = 0; q < 2; ++q) {
                float4 a4 = *(const float4*)&x[(size_t)gr * 128 + c0 + q * 8];
                float4 b4 = *(const float4*)&x[(size_t)gr * 128 + c0 + q * 8 + 4];
                u16x8 pk;
                pk[0] = f2b(a4.x); pk[1] = f2b(a4.y); pk[2] = f2b(a4.z); pk[3] = f2b(a4.w);
                pk[4] = f2b(b4.x); pk[5] = f2b(b4.y); pk[6] = f2b(b4.z); pk[7] = f2b(b4.w);
                if (q == 0) pk0 = pk; else pk1 = pk;
            }
        } else {
            #pragma unroll
            for (int i = 0; i < 8; ++i) { pk0[i] = 0; pk1[i] = 0; }
        }
        int base = r * 256 + c0 * 2;
        *(u16x8*)(xbA + (base ^ SWZ(r))) = pk0;
        *(u16x8*)(xbA + ((base + 16) ^ SWZ(r))) = pk1;
    }
    __syncthreads();

    int wv = t >> 6, l = t & 63;
    int lr = l & 15, lg = l >> 4;

    f32x4 acc[4] = {};
    #pragma unroll
    for (int ks = 0; ks < 4; ++ks) {
        bf16x8 b = *(const bf16x8*)(WpT + (wv * 16 + lr) * 128 + ks * 32 + lg * 8);
        #pragma unroll
        for (int mi = 0; mi < 4; ++mi) {
            int row = mi * 16 + lr;
            int off = (row * 256 + ks * 64 + lg * 16) ^ SWZ(row);
            bf16x8 a = *(const bf16x8*)(xbA + off);
            acc[mi] = __builtin_amdgcn_mfma_f32_16x16x32_bf16(a, b, acc[mi], 0, 0, 0);
        }
    }

    float alv = a_l[wv * 16 + lr];
    float arv = a_r[wv * 16 + lr];
    float outL = 0.f, outR = 0.f;
    #pragma unroll
    for (int mi = 0; mi < 4; ++mi) {
        #pragma unroll
        for (int rg = 0; rg < 4; ++rg) {
            int row = mi * 16 + lg * 4 + rg;
            int grr = r0 + row;
            float v = acc[mi][rg];
            if (grr < N_NODES) zb[(size_t)grr * 128 + wv * 16 + lr] = f2b(v);
            float pl = v * alv, pr = v * arv;
            pl += __shfl_xor(pl, 1); pr += __shfl_xor(pr, 1);
            pl += __shfl_xor(pl, 2); pr += __shfl_xor(pr, 2);
            pl += __shfl_xor(pl, 4); pr += __shfl_xor(pr, 4);
            pl += __shfl_xor(pl, 8); pr += __shfl_xor(pr, 8);
            if (lr == mi * 4 + rg) { outL = pl; outR = pr; }
        }
    }
    int myrow = r0 + (lr >> 2) * 16 + lg * 4 + (lr & 3);
    if (myrow < N_NODES) {
        el[myrow * 8 + wv] = outL;
        er[myrow * 8 + wv] = outR;
    }
}

// ---------------- fused softmax + aggregate + elu + residual ----------------
__global__ __launch_bounds__(256) void k_node(const int* __restrict__ csr_off,
                                              const int* __restrict__ csr_src,
                                              const float* __restrict__ el,
                                              const float* __restrict__ er,
                                              const unsigned short* __restrict__ zb,
                                              const float* __restrict__ x,
                                              float* __restrict__ out) {
    int n = blockIdx.x * 8 + (threadIdx.x >> 5);
    int lane = threadIdx.x & 63;
    int q = lane & 31;
    int base = lane & 32;       // shuffle base of this half-wave
    int h = q >> 2, s = q & 3;
    int row = csr_off[n];
    int deg = csr_off[n + 1] - row;
    float4 xv = *(const float4*)&x[(size_t)n * 128 + q * 4];
    float erv = er[n * 8 + h];
    int nch = (deg + 3) >> 2;

    float ps = 0.f;
    float ac0 = 0.f, ac1 = 0.f, ac2 = 0.f, ac3 = 0.f;
    const unsigned short* zbl = zb + q * 4;
    #pragma unroll
    for (int c = 0; c < 8; ++c) {
        if (c * 4 < deg) {  // uniform across half-wave
            int k = c * 4 + s;
            int kk = min(k, deg - 1);          // branch-free clamp
            int src = csr_src[row + kk];
            float e = lrelu(el[src * 8 + h] + erv);
            float p = (k < deg) ? __expf(e) : 0.f;
            ps += p;
            float a[4];
            int se[4];
            #pragma unroll
            for (int tt = 0; tt < 4; ++tt) {
                a[tt] = __shfl(p, base + h * 4 + tt);
                se[tt] = __shfl(src, base + tt);
            }
            uint2 u[4];
            #pragma unroll
            for (int tt = 0; tt < 4; ++tt)
                u[tt] = *(const uint2*)(zbl + (size_t)se[tt] * 128);
            #pragma unroll
            for (int tt = 0; tt < 4; ++tt) {
                ac0 += a[tt] * __uint_as_float(u[tt].x << 16);
                ac1 += a[tt] * __uint_as_float(u[tt].x & 0xFFFF0000u);
                ac2 += a[tt] * __uint_as_float(u[tt].y << 16);
                ac3 += a[tt] * __uint_as_float(u[tt].y & 0xFFFF0000u);
            }
        }
    }
    for (int c = 8; c < nch; ++c) {  // rare: deg > 32
        int k = c * 4 + s;
        int kk = min(k, deg - 1);
        int src = csr_src[row + kk];
        float e = lrelu(el[src * 8 + h] + erv);
        float p = (k < deg) ? __expf(e) : 0.f;
        ps += p;
        float a[4];
        int se[4];
        #pragma unroll
        for (int tt = 0; tt < 4; ++tt) {
            a[tt] = __shfl(p, base + h * 4 + tt);
            se[tt] = __shfl(src, base + tt);
        }
        uint2 u[4];
        #pragma unroll
        for (int tt = 0; tt < 4; ++tt)
            u[tt] = *(const uint2*)(zbl + (size_t)se[tt] * 128);
        #pragma unroll
        for (int tt = 0; tt < 4; ++tt) {
            ac0 += a[tt] * __uint_as_float(u[tt].x << 16);
            ac1 += a[tt] * __uint_as_float(u[tt].x & 0xFFFF0000u);
            ac2 += a[tt] * __uint_as_float(u[tt].y << 16);
            ac3 += a[tt] * __uint_as_float(u[tt].y & 0xFFFF0000u);
        }
    }
    // per-head sum over the 4 edge slots (bits 0,1 of q)
    ps += __shfl_xor(ps, 1);
    ps += __shfl_xor(ps, 2);
    float inv = 1.f / fmaxf(ps, 1e-9f);
    float4 hv;
    hv.x = xv.x + elu(ac0 * inv);
    hv.y = xv.y + elu(ac1 * inv);
    hv.z = xv.z + elu(ac2 * inv);
    hv.w = xv.w + elu(ac3 * inv);
    *(float4*)&out[(size_t)n * 128 + q * 4] = hv;
}

// ---------------- FFN: weight-stationary persistent kernel + pipelined LN ---
// Software pipeline restored: next tile's h (hvv_n/h4_n) is loaded BEFORE
// GEMM1 and consumed (LN-pack) only after the epilogue -> HBM/L3 latency
// hides under 64 MFMAs + LDS phases (the R18 regression was this missing).
__global__ __launch_bounds__(256, 1) void k_ffn(const bf16_t* __restrict__ W1T,
                                                const float* __restrict__ b1,
                                                const bf16_t* __restrict__ W2T,
                                                const float* __restrict__ b2,
                                                const float* __restrict__ gamma,
                                                const float* __restrict__ beta,
                                                float* __restrict__ out) {
    __shared__ char inA[16384];  // bf16[16 nodes][512 f], row 1024B, swz by node
    int t = threadIdx.x;
    int w = t >> 6, l = t & 63;
    int lr = l & 15, lg = l >> 4;

    bf16x8 w1f[4][8];
    #pragma unroll
    for (int ks = 0; ks < 4; ++ks)
        #pragma unroll
        for (int tf = 0; tf < 8; ++tf)
            w1f[ks][tf] = *(const bf16x8*)(W1T + (size_t)(w * 128 + tf * 16 + lr) * 128 + ks * 32 + lg * 8);
    bf16x8 w2f[16][2];
    #pragma unroll
    for (int ks2 = 0; ks2 < 16; ++ks2)
        #pragma unroll
        for (int tc = 0; tc < 2; ++tc)
            w2f[ks2][tc] = *(const bf16x8*)(W2T + (size_t)(w * 32 + tc * 16 + lr) * 512 + ks2 * 32 + lg * 8);
    float4 b1v[8];
    #pragma unroll
    for (int tf = 0; tf < 8; ++tf)
        b1v[tf] = *(const float4*)&b1[w * 128 + tf * 16 + lg * 4];
    float4 b2v[2];
    #pragma unroll
    for (int tc = 0; tc < 2; ++tc)
        b2v[tc] = *(const float4*)&b2[w * 32 + tc * 16 + lg * 4];

    int tile = blockIdx.x;

    // prologue: load tile0's h and LN-pack it
    float4 h4[2];
    bf16x8 cur[4];
    {
        const float* hb = out + (size_t)(tile * 16 + lr) * 128;
        float hvv[4][8];
        float sm = 0.f, sq = 0.f;
        #pragma unroll
        for (int ks = 0; ks < 4; ++ks) {
            float4 A = *(const float4*)(hb + ks * 32 + lg * 8);
            float4 B = *(const float4*)(hb + ks * 32 + lg * 8 + 4);
            hvv[ks][0] = A.x; hvv[ks][1] = A.y; hvv[ks][2] = A.z; hvv[ks][3] = A.w;
            hvv[ks][4] = B.x; hvv[ks][5] = B.y; hvv[ks][6] = B.z; hvv[ks][7] = B.w;
            #pragma unroll
            for (int j = 0; j < 8; ++j) { sm += hvv[ks][j]; sq += hvv[ks][j] * hvv[ks][j]; }
        }
        #pragma unroll
        for (int tc = 0; tc < 2; ++tc)
            h4[tc] = *(const float4*)(hb + w * 32 + tc * 16 + lg * 4);
        sm += __shfl_xor(sm, 16); sq += __shfl_xor(sq, 16);
        sm += __shfl_xor(sm, 32); sq += __shfl_xor(sq, 32);
        float mu = sm * (1.f / 128.f);
        float rs = rsqrtf(sq * (1.f / 128.f) - mu * mu + 1e-5f);
        #pragma unroll
        for (int ks = 0; ks < 4; ++ks) {
            float4 g0 = *(const float4*)&gamma[ks * 32 + lg * 8];
            float4 g1 = *(const float4*)&gamma[ks * 32 + lg * 8 + 4];
            float4 be0 = *(const float4*)&beta[ks * 32 + lg * 8];
            float4 be1 = *(const float4*)&beta[ks * 32 + lg * 8 + 4];
            float ga[8] = {g0.x, g0.y, g0.z, g0.w, g1.x, g1.y, g1.z, g1.w};
            float ba[8] = {be0.x, be0.y, be0.z, be0.w, be1.x, be1.y, be1.z, be1.w};
            u16x8 pk;
            #pragma unroll
            for (int j = 0; j < 8; ++j)
                pk[j] = f2b((hvv[ks][j] - mu) * rs * ga[j] + ba[j]);
            cur[ks] = __builtin_bit_cast(bf16x8, pk);
        }
    }

    while (tile < NTILES) {
        int tn = tile + FFN_GRID;
        // issue next tile's h loads EARLY (consumed after epilogue)
        float hvv_n[4][8];
        float4 h4n[2];
        if (tn < NTILES) {
            const float* hn = out + (size_t)(tn * 16 + lr) * 128;
            #pragma unroll
            for (int ks = 0; ks < 4; ++ks) {
                float4 A = *(const float4*)(hn + ks * 32 + lg * 8);
                float4 B = *(const float4*)(hn + ks * 32 + lg * 8 + 4);
                hvv_n[ks][0] = A.x; hvv_n[ks][1] = A.y; hvv_n[ks][2] = A.z; hvv_n[ks][3] = A.w;
                hvv_n[ks][4] = B.x; hvv_n[ks][5] = B.y; hvv_n[ks][6] = B.z; hvv_n[ks][7] = B.w;
            }
            #pragma unroll
            for (int tc = 0; tc < 2; ++tc)
                h4n[tc] = *(const float4*)(hn + w * 32 + tc * 16 + lg * 4);
        }

        // GEMM1
        f32x4 p[8] = {};
        #pragma unroll
        for (int ks = 0; ks < 4; ++ks)
            #pragma unroll
            for (int tf = 0; tf < 8; ++tf)
                p[tf] = __builtin_amdgcn_mfma_f32_16x16x32_bf16(w1f[ks][tf], cur[ks], p[tf], 0, 0, 0);

        #pragma unroll
        for (int tf = 0; tf < 8; ++tf) {
            float4 bb = b1v[tf];
            ushort4 pk;
            float v0 = p[tf][0] + bb.x; pk.x = f2b(v0 > 0.f ? v0 : 0.f);
            float v1 = p[tf][1] + bb.y; pk.y = f2b(v1 > 0.f ? v1 : 0.f);
            float v2 = p[tf][2] + bb.z; pk.z = f2b(v2 > 0.f ? v2 : 0.f);
            float v3 = p[tf][3] + bb.w; pk.w = f2b(v3 > 0.f ? v3 : 0.f);
            *(ushort4*)(inA + ((lr * 1024 + w * 256 + tf * 32 + lg * 8) ^ SWZ(lr))) = pk;
        }
        __syncthreads();

        // GEMM2
        f32x4 Q[2] = {};
        #pragma unroll
        for (int ks2 = 0; ks2 < 16; ++ks2) {
            bf16x8 bfr = *(const bf16x8*)(inA + ((lr * 1024 + ks2 * 64 + lg * 16) ^ SWZ(lr)));
            #pragma unroll
            for (int tc = 0; tc < 2; ++tc)
                Q[tc] = __builtin_amdgcn_mfma_f32_16x16x32_bf16(w2f[ks2][tc], bfr, Q[tc], 0, 0, 0);
        }

        // epilogue (uses current tile's h4)
        #pragma unroll
        for (int tc = 0; tc < 2; ++tc) {
            float4 o4;
            o4.x = Q[tc][0] + b2v[tc].x + h4[tc].x;
            o4.y = Q[tc][1] + b2v[tc].y + h4[tc].y;
            o4.z = Q[tc][2] + b2v[tc].z + h4[tc].z;
            o4.w = Q[tc][3] + b2v[tc].w + h4[tc].w;
            *(float4*)(out + (size_t)(tile * 16 + lr) * 128 + w * 32 + tc * 16 + lg * 4) = o4;
        }
        __syncthreads();

        // rotate pipeline: LN-pack prefetched tile
        if (tn < NTILES) {
            float sm = 0.f, sq = 0.f;
            #pragma unroll
            for (int ks = 0; ks < 4; ++ks)
                #pragma unroll
                for (int j = 0; j < 8; ++j) { sm += hvv_n[ks][j]; sq += hvv_n[ks][j] * hvv_n[ks][j]; }
            sm += __shfl_xor(sm, 16); sq += __shfl_xor(sq, 16);
            sm += __shfl_xor(sm, 32); sq += __shfl_xor(sq, 32);
            float mu = sm * (1.f / 128.f);
            float rs = rsqrtf(sq * (1.f / 128.f) - mu * mu + 1e-5f);
            #pragma unroll
            for (int ks = 0; ks < 4; ++ks) {
                float4 g0 = *(const float4*)&gamma[ks * 32 + lg * 8];
                float4 g1 = *(const float4*)&gamma[ks * 32 + lg * 8 + 4];
                float4 be0 = *(const float4*)&beta[ks * 32 + lg * 8];
                float4 be1 = *(const float4*)&beta[ks * 32 + lg * 8 + 4];
                float ga[8] = {g0.x, g0.y, g0.z, g0.w, g1.x, g1.y, g1.z, g1.w};
                float ba[8] = {be0.x, be0.y, be0.z, be0.w, be1.x, be1.y, be1.z, be1.w};
                u16x8 pk;
                #pragma unroll
                for (int j = 0; j < 8; ++j)
                    pk[j] = f2b((hvv_n[ks][j] - mu) * rs * ga[j] + ba[j]);
                cur[ks] = __builtin_bit_cast(bf16x8, pk);
            }
            h4[0] = h4n[0];
            h4[1] = h4n[1];
        }
        tile = tn;
    }
}

extern "C" void kernel_launch(void* const* d_in, const int* in_sizes, int n_in,
                              void* d_out, int out_size, void* d_ws, size_t ws_size,
                              hipStream_t stream) {
    const float* x     = (const float*)d_in[0];
    const float* Wfc   = (const float*)d_in[1];
    const float* a_l   = (const float*)d_in[2];
    const float* a_r   = (const float*)d_in[3];
    const float* gamma = (const float*)d_in[4];
    const float* beta  = (const float*)d_in[5];
    const float* W1    = (const float*)d_in[6];
    const float* b1    = (const float*)d_in[7];
    const float* W2    = (const float*)d_in[8];
    const float* b2    = (const float*)d_in[9];
    const int*   es    = (const int*)d_in[10];
    const int*   ed    = (const int*)d_in[11];
    float* out = (float*)d_out;

    bf16_t* W1T = (bf16_t*)d_ws;                      // 512*128
    bf16_t* W2T = W1T + 512 * 128;                    // 128*512
    bf16_t* WpT = W2T + 128 * 512;                    // 128*128
    unsigned short* zb = (unsigned short*)(WpT + 128 * 128);  // N*128 bf16 (node-major)
    float* el = (float*)(zb + (size_t)N_NODES * 128); // N*8 (node-major)
    float* er = el + N_NODES * 8;                     // N*8
    int* counts  = (int*)(er + N_NODES * 8);          // N
    int* csr_off = counts + N_NODES;                  // N+1
    int* csr_src = csr_off + N_NODES + 1;             // E
    int* rank    = csr_src + E_EDGES;                 // E
    int* bsum    = rank + E_EDGES;                    // 128
    int* boff    = bsum + 128;                        // 128

    k_prep<<<dim3(256), dim3(256), 0, stream>>>(W1, W2, Wfc, W1T, W2T, WpT, counts);
    k_count<<<dim3((E_EDGES + 255) / 256), dim3(256), 0, stream>>>(ed, counts, rank);
    k_scan1<<<dim3(SCAN_BLOCKS), dim3(512), 0, stream>>>(counts, bsum);
    k_scan2<<<dim3(1), dim3(128), 0, stream>>>(bsum, boff);
    k_scan3<<<dim3(SCAN_BLOCKS), dim3(512), 0, stream>>>(counts, boff, csr_off);
    k_fillproj<<<dim3(PROJ_BLOCKS + FILL_BLOCKS), dim3(512), 0, stream>>>(
        x, WpT, a_l, a_r, zb, el, er, es, ed, rank, csr_off, csr_src);
    k_node<<<dim3(N_NODES / 8), dim3(256), 0, stream>>>(csr_off, csr_src, el, er, zb, x, out);
    k_ffn<<<dim3(FFN_GRID), dim3(256), 0, stream>>>(W1T, b1, W2T, b2, gamma, beta, out);
}

// Round 20
// 152.679 us; speedup vs baseline: 1.6490x; 1.0980x over previous
//
#include <hip/hip_runtime.h>
#include <math.h>

#define N_NODES 50000
#define E_EDGES 800000
#define D_DIM   128
#define H_HEADS 8
#define DH_DIM  16
#define DFF     512

#define SCAN_BLOCKS 98  // 98*512 = 50176 >= N_NODES+1
#define FFN_GRID 256
#define NTILES 3125     // 50000 / 16 exactly
#define PROJ_BLOCKS 782 // ceil(50000/64)
#define FILL_BLOCKS 782 // ceil(800000/1024)

typedef __bf16 bf16_t;
typedef bf16_t bf16x8 __attribute__((ext_vector_type(8)));
typedef float f32x4 __attribute__((ext_vector_type(4)));
typedef unsigned short u16x8 __attribute__((ext_vector_type(8)));

#define SWZ(r) (((r) & 7) << 4)

__device__ __forceinline__ float lrelu(float v) { return v > 0.f ? v : 0.01f * v; }
__device__ __forceinline__ float elu(float v) { return v > 0.f ? v : __expf(v) - 1.f; }
__device__ __forceinline__ unsigned short f2b(float f) {
    unsigned u = __float_as_uint(f);
    unsigned r = (u + 0x7FFFu + ((u >> 16) & 1u)) >> 16;
    return (unsigned short)r;
}

// ---------------- count in-degree + capture rank ----------------
__global__ void k_count(const int* __restrict__ ed, int* __restrict__ counts,
                        int* __restrict__ rank) {
    int e = blockIdx.x * 256 + threadIdx.x;
    if (e < E_EDGES) rank[e] = atomicAdd(&counts[ed[e]], 1);
}

// ---------------- hierarchical scan ----------------
__global__ __launch_bounds__(512) void k_scan1(const int* __restrict__ counts,
                                               int* __restrict__ bsum) {
    int i = blockIdx.x * 512 + threadIdx.x;
    int v = (i < N_NODES) ? counts[i] : 0;
    #pragma unroll
    for (int o = 1; o < 64; o <<= 1) v += __shfl_xor(v, o);
    __shared__ int ws[8];
    if ((threadIdx.x & 63) == 0) ws[threadIdx.x >> 6] = v;
    __syncthreads();
    if (threadIdx.x == 0) {
        int s = 0;
        #pragma unroll
        for (int k = 0; k < 8; ++k) s += ws[k];
        bsum[blockIdx.x] = s;
    }
}

__global__ __launch_bounds__(128) void k_scan2(const int* __restrict__ bsum,
                                               int* __restrict__ boff) {
    __shared__ int tmp[128];
    int t = threadIdx.x;
    int v = (t < SCAN_BLOCKS) ? bsum[t] : 0;
    tmp[t] = v;
    __syncthreads();
    for (int o = 1; o < 128; o <<= 1) {
        int u = (t >= o) ? tmp[t - o] : 0;
        __syncthreads();
        tmp[t] += u;
        __syncthreads();
    }
    boff[t] = (t == 0) ? 0 : tmp[t - 1];
}

__global__ __launch_bounds__(512) void k_scan3(const int* __restrict__ counts,
                                               const int* __restrict__ boff,
                                               int* __restrict__ csr_off) {
    int t = threadIdx.x;
    int i = blockIdx.x * 512 + t;
    int v = (i < N_NODES) ? counts[i] : 0;
    int lane = t & 63, w = t >> 6;
    int xs = v;
    #pragma unroll
    for (int o = 1; o < 64; o <<= 1) {
        int u = __shfl_up(xs, o);
        if (lane >= o) xs += u;
    }
    __shared__ int ws[8];
    __shared__ int wo[8];
    if (lane == 63) ws[w] = xs;
    __syncthreads();
    if (t == 0) {
        int s = 0;
        #pragma unroll
        for (int k = 0; k < 8; ++k) { wo[k] = s; s += ws[k]; }
    }
    __syncthreads();
    int excl = xs - v + wo[w] + boff[blockIdx.x];
    if (i < N_NODES) csr_off[i] = excl;
    if (i == N_NODES) csr_off[N_NODES] = E_EDGES;
}

// ---------------- weight prep: transpose + bf16 (+ fused counts zero) -------
__global__ void k_prep(const float* __restrict__ W1, const float* __restrict__ W2,
                       const float* __restrict__ Wfc,
                       bf16_t* __restrict__ W1T, bf16_t* __restrict__ W2T,
                       bf16_t* __restrict__ WpT, int* __restrict__ counts) {
    int id = blockIdx.x * 256 + threadIdx.x;
    if (id < N_NODES) counts[id] = 0;
    if (id < 512 * 128) {
        int c = id >> 7, k = id & 127;
        W1T[id] = (bf16_t)W1[(size_t)k * 512 + c];
        int c2 = id >> 9, k2 = id & 511;
        W2T[id] = (bf16_t)W2[(size_t)k2 * 128 + c2];
        if (id < 128 * 128) {
            int cp = id >> 7, kp = id & 127;
            WpT[id] = (bf16_t)Wfc[(cp >> 4) * 2048 + kp * 16 + (cp & 15)];
        }
    }
}

// ---------------- FUSED: proj (MFMA) blocks || CSR-fill (scatter) blocks ----
__global__ __launch_bounds__(512) void k_fillproj(const float* __restrict__ x,
                                                  const bf16_t* __restrict__ WpT,
                                                  const float* __restrict__ a_l,
                                                  const float* __restrict__ a_r,
                                                  unsigned short* __restrict__ zb,
                                                  float* __restrict__ el,
                                                  float* __restrict__ er,
                                                  const int* __restrict__ es,
                                                  const int* __restrict__ ed,
                                                  const int* __restrict__ rank,
                                                  const int* __restrict__ csr_off,
                                                  int* __restrict__ csr_src) {
    __shared__ char xbA[16384];  // bf16[64][128], row stride 256B, swizzled
    int t = threadIdx.x;

    if (blockIdx.x >= PROJ_BLOCKS) {
        // ---- fill branch: 1024 edges/block, no atomics ----
        int e0 = (blockIdx.x - PROJ_BLOCKS) * 1024 + t;
        #pragma unroll
        for (int k = 0; k < 2; ++k) {
            int e = e0 + k * 512;
            if (e < E_EDGES) {
                int d = ed[e];
                csr_src[csr_off[d] + rank[e]] = es[e];
            }
        }
        return;
    }

    // ---- proj branch ----
    int r0 = blockIdx.x * 64;
    {
        int r = t >> 3, c0 = (t & 7) * 16;
        int gr = r0 + r;
        u16x8 pk0, pk1;
        if (gr < N_NODES) {
            #pragma unroll
            for (int q = 0; q < 2; ++q) {
                float4 a4 = *(const float4*)&x[(size_t)gr * 128 + c0 + q * 8];
                float4 b4 = *(const float4*)&x[(size_t)gr * 128 + c0 + q * 8 + 4];
                u16x8 pk;
                pk[0] = f2b(a4.x); pk[1] = f2b(a4.y); pk[2] = f2b(a4.z); pk[3] = f2b(a4.w);
                pk[4] = f2b(b4.x); pk[5] = f2b(b4.y); pk[6] = f2b(b4.z); pk[7] = f2b(b4.w);
                if (q == 0) pk0 = pk; else pk1 = pk;
            }
        } else {
            #pragma unroll
            for (int i = 0; i < 8; ++i) { pk0[i] = 0; pk1[i] = 0; }
        }
        int base = r * 256 + c0 * 2;
        *(u16x8*)(xbA + (base ^ SWZ(r))) = pk0;
        *(u16x8*)(xbA + ((base + 16) ^ SWZ(r))) = pk1;
    }
    __syncthreads();

    int wv = t >> 6, l = t & 63;
    int lr = l & 15, lg = l >> 4;

    f32x4 acc[4] = {};
    #pragma unroll
    for (int ks = 0; ks < 4; ++ks) {
        bf16x8 b = *(const bf16x8*)(WpT + (wv * 16 + lr) * 128 + ks * 32 + lg * 8);
        #pragma unroll
        for (int mi = 0; mi < 4; ++mi) {
            int row = mi * 16 + lr;
            int off = (row * 256 + ks * 64 + lg * 16) ^ SWZ(row);
            bf16x8 a = *(const bf16x8*)(xbA + off);
            acc[mi] = __builtin_amdgcn_mfma_f32_16x16x32_bf16(a, b, acc[mi], 0, 0, 0);
        }
    }

    float alv = a_l[wv * 16 + lr];
    float arv = a_r[wv * 16 + lr];
    float outL = 0.f, outR = 0.f;
    #pragma unroll
    for (int mi = 0; mi < 4; ++mi) {
        #pragma unroll
        for (int rg = 0; rg < 4; ++rg) {
            int row = mi * 16 + lg * 4 + rg;
            int grr = r0 + row;
            float v = acc[mi][rg];
            if (grr < N_NODES) zb[(size_t)grr * 128 + wv * 16 + lr] = f2b(v);
            float pl = v * alv, pr = v * arv;
            pl += __shfl_xor(pl, 1); pr += __shfl_xor(pr, 1);
            pl += __shfl_xor(pl, 2); pr += __shfl_xor(pr, 2);
            pl += __shfl_xor(pl, 4); pr += __shfl_xor(pr, 4);
            pl += __shfl_xor(pl, 8); pr += __shfl_xor(pr, 8);
            if (lr == mi * 4 + rg) { outL = pl; outR = pr; }
        }
    }
    int myrow = r0 + (lr >> 2) * 16 + lg * 4 + (lr & 3);
    if (myrow < N_NODES) {
        el[myrow * 8 + wv] = outL;
        er[myrow * 8 + wv] = outR;
    }
}

// ---------------- fused softmax + aggregate + elu + residual + LN -----------
// SINGLE PASS (softmax shift-invariance; e bounded). LN tail writes lnb bf16.
__global__ __launch_bounds__(256) void k_node(const int* __restrict__ csr_off,
                                              const int* __restrict__ csr_src,
                                              const float* __restrict__ el,
                                              const float* __restrict__ er,
                                              const unsigned short* __restrict__ zb,
                                              const float* __restrict__ x,
                                              const float* __restrict__ gamma,
                                              const float* __restrict__ beta,
                                              unsigned short* __restrict__ lnb,
                                              float* __restrict__ out) {
    int n = blockIdx.x * 8 + (threadIdx.x >> 5);
    int lane = threadIdx.x & 63;
    int q = lane & 31;
    int base = lane & 32;       // shuffle base of this half-wave
    int h = q >> 2, s = q & 3;
    int row = csr_off[n];
    int deg = csr_off[n + 1] - row;
    float4 xv = *(const float4*)&x[(size_t)n * 128 + q * 4];
    float erv = er[n * 8 + h];
    int nch = (deg + 3) >> 2;

    float ps = 0.f;
    float ac0 = 0.f, ac1 = 0.f, ac2 = 0.f, ac3 = 0.f;
    const unsigned short* zbl = zb + q * 4;
    #pragma unroll
    for (int c = 0; c < 8; ++c) {
        if (c * 4 < deg) {  // uniform across half-wave
            int k = c * 4 + s;
            int kk = min(k, deg - 1);          // branch-free clamp
            int src = csr_src[row + kk];
            float e = lrelu(el[src * 8 + h] + erv);
            float p = (k < deg) ? __expf(e) : 0.f;
            ps += p;
            float a[4];
            int se[4];
            #pragma unroll
            for (int tt = 0; tt < 4; ++tt) {
                a[tt] = __shfl(p, base + h * 4 + tt);
                se[tt] = __shfl(src, base + tt);
            }
            uint2 u[4];
            #pragma unroll
            for (int tt = 0; tt < 4; ++tt)
                u[tt] = *(const uint2*)(zbl + (size_t)se[tt] * 128);
            #pragma unroll
            for (int tt = 0; tt < 4; ++tt) {
                ac0 += a[tt] * __uint_as_float(u[tt].x << 16);
                ac1 += a[tt] * __uint_as_float(u[tt].x & 0xFFFF0000u);
                ac2 += a[tt] * __uint_as_float(u[tt].y << 16);
                ac3 += a[tt] * __uint_as_float(u[tt].y & 0xFFFF0000u);
            }
        }
    }
    for (int c = 8; c < nch; ++c) {  // rare: deg > 32
        int k = c * 4 + s;
        int kk = min(k, deg - 1);
        int src = csr_src[row + kk];
        float e = lrelu(el[src * 8 + h] + erv);
        float p = (k < deg) ? __expf(e) : 0.f;
        ps += p;
        float a[4];
        int se[4];
        #pragma unroll
        for (int tt = 0; tt < 4; ++tt) {
            a[tt] = __shfl(p, base + h * 4 + tt);
            se[tt] = __shfl(src, base + tt);
        }
        uint2 u[4];
        #pragma unroll
        for (int tt = 0; tt < 4; ++tt)
            u[tt] = *(const uint2*)(zbl + (size_t)se[tt] * 128);
        #pragma unroll
        for (int tt = 0; tt < 4; ++tt) {
            ac0 += a[tt] * __uint_as_float(u[tt].x << 16);
            ac1 += a[tt] * __uint_as_float(u[tt].x & 0xFFFF0000u);
            ac2 += a[tt] * __uint_as_float(u[tt].y << 16);
            ac3 += a[tt] * __uint_as_float(u[tt].y & 0xFFFF0000u);
        }
    }
    ps += __shfl_xor(ps, 1);
    ps += __shfl_xor(ps, 2);
    float inv = 1.f / fmaxf(ps, 1e-9f);
    float4 hv;
    hv.x = xv.x + elu(ac0 * inv);
    hv.y = xv.y + elu(ac1 * inv);
    hv.z = xv.z + elu(ac2 * inv);
    hv.w = xv.w + elu(ac3 * inv);
    *(float4*)&out[(size_t)n * 128 + q * 4] = hv;

    // LayerNorm over the 128 dims held by this half-wave (32 lanes x 4)
    float rsm = hv.x + hv.y + hv.z + hv.w;
    float rsq = hv.x * hv.x + hv.y * hv.y + hv.z * hv.z + hv.w * hv.w;
    #pragma unroll
    for (int o = 1; o <= 16; o <<= 1) {
        rsm += __shfl_xor(rsm, o);
        rsq += __shfl_xor(rsq, o);
    }
    float mu = rsm * (1.f / 128.f);
    float rs = rsqrtf(rsq * (1.f / 128.f) - mu * mu + 1e-5f);
    float4 g4 = *(const float4*)&gamma[q * 4];
    float4 be4 = *(const float4*)&beta[q * 4];
    ushort4 pk;
    pk.x = f2b((hv.x - mu) * rs * g4.x + be4.x);
    pk.y = f2b((hv.y - mu) * rs * g4.y + be4.y);
    pk.z = f2b((hv.z - mu) * rs * g4.z + be4.z);
    pk.w = f2b((hv.w - mu) * rs * g4.w + be4.w);
    *(ushort4*)&lnb[(size_t)n * 128 + q * 4] = pk;
}

// ---------------- FFN: weight-stationary persistent kernel -----------------
__global__ __launch_bounds__(256, 1) void k_ffn(const bf16_t* __restrict__ W1T,
                                                const float* __restrict__ b1,
                                                const bf16_t* __restrict__ W2T,
                                                const float* __restrict__ b2,
                                                const unsigned short* __restrict__ lnb,
                                                float* __restrict__ out) {
    __shared__ char inA[16384];  // bf16[16 nodes][512 f], row 1024B, swz by node
    int t = threadIdx.x;
    int w = t >> 6, l = t & 63;
    int lr = l & 15, lg = l >> 4;

    bf16x8 w1f[4][8];
    #pragma unroll
    for (int ks = 0; ks < 4; ++ks)
        #pragma unroll
        for (int tf = 0; tf < 8; ++tf)
            w1f[ks][tf] = *(const bf16x8*)(W1T + (size_t)(w * 128 + tf * 16 + lr) * 128 + ks * 32 + lg * 8);
    bf16x8 w2f[16][2];
    #pragma unroll
    for (int ks2 = 0; ks2 < 16; ++ks2)
        #pragma unroll
        for (int tc = 0; tc < 2; ++tc)
            w2f[ks2][tc] = *(const bf16x8*)(W2T + (size_t)(w * 32 + tc * 16 + lr) * 512 + ks2 * 32 + lg * 8);
    float4 b1v[8];
    #pragma unroll
    for (int tf = 0; tf < 8; ++tf)
        b1v[tf] = *(const float4*)&b1[w * 128 + tf * 16 + lg * 4];
    float4 b2v[2];
    #pragma unroll
    for (int tc = 0; tc < 2; ++tc)
        b2v[tc] = *(const float4*)&b2[w * 32 + tc * 16 + lg * 4];

    int tile = blockIdx.x;
    bf16x8 cur[4];
    #pragma unroll
    for (int ks = 0; ks < 4; ++ks)
        cur[ks] = *(const bf16x8*)(lnb + (size_t)(tile * 16 + lr) * 128 + ks * 32 + lg * 8);

    while (tile < NTILES) {
        float4 h4[2];
        #pragma unroll
        for (int tc = 0; tc < 2; ++tc)
            h4[tc] = *(const float4*)(out + (size_t)(tile * 16 + lr) * 128 + w * 32 + tc * 16 + lg * 4);

        f32x4 p[8] = {};
        #pragma unroll
        for (int ks = 0; ks < 4; ++ks)
            #pragma unroll
            for (int tf = 0; tf < 8; ++tf)
                p[tf] = __builtin_amdgcn_mfma_f32_16x16x32_bf16(w1f[ks][tf], cur[ks], p[tf], 0, 0, 0);

        int tn = tile + FFN_GRID;
        if (tn < NTILES) {
            #pragma unroll
            for (int ks = 0; ks < 4; ++ks)
                cur[ks] = *(const bf16x8*)(lnb + (size_t)(tn * 16 + lr) * 128 + ks * 32 + lg * 8);
        }

        #pragma unroll
        for (int tf = 0; tf < 8; ++tf) {
            float4 bb = b1v[tf];
            ushort4 pk;
            float v0 = p[tf][0] + bb.x; pk.x = f2b(v0 > 0.f ? v0 : 0.f);
            float v1 = p[tf][1] + bb.y; pk.y = f2b(v1 > 0.f ? v1 : 0.f);
            float v2 = p[tf][2] + bb.z; pk.z = f2b(v2 > 0.f ? v2 : 0.f);
            float v3 = p[tf][3] + bb.w; pk.w = f2b(v3 > 0.f ? v3 : 0.f);
            *(ushort4*)(inA + ((lr * 1024 + w * 256 + tf * 32 + lg * 8) ^ SWZ(lr))) = pk;
        }
        __syncthreads();

        f32x4 Q[2] = {};
        #pragma unroll
        for (int ks2 = 0; ks2 < 16; ++ks2) {
            bf16x8 bfr = *(const bf16x8*)(inA + ((lr * 1024 + ks2 * 64 + lg * 16) ^ SWZ(lr)));
            #pragma unroll
            for (int tc = 0; tc < 2; ++tc)
                Q[tc] = __builtin_amdgcn_mfma_f32_16x16x32_bf16(w2f[ks2][tc], bfr, Q[tc], 0, 0, 0);
        }

        #pragma unroll
        for (int tc = 0; tc < 2; ++tc) {
            float4 o4;
            o4.x = Q[tc][0] + b2v[tc].x + h4[tc].x;
            o4.y = Q[tc][1] + b2v[tc].y + h4[tc].y;
            o4.z = Q[tc][2] + b2v[tc].z + h4[tc].z;
            o4.w = Q[tc][3] + b2v[tc].w + h4[tc].w;
            *(float4*)(out + (size_t)(tile * 16 + lr) * 128 + w * 32 + tc * 16 + lg * 4) = o4;
        }
        __syncthreads();
        tile = tn;
    }
}

extern "C" void kernel_launch(void* const* d_in, const int* in_sizes, int n_in,
                              void* d_out, int out_size, void* d_ws, size_t ws_size,
                              hipStream_t stream) {
    const float* x     = (const float*)d_in[0];
    const float* Wfc   = (const float*)d_in[1];
    const float* a_l   = (const float*)d_in[2];
    const float* a_r   = (const float*)d_in[3];
    const float* gamma = (const float*)d_in[4];
    const float* beta  = (const float*)d_in[5];
    const float* W1    = (const float*)d_in[6];
    const float* b1    = (const float*)d_in[7];
    const float* W2    = (const float*)d_in[8];
    const float* b2    = (const float*)d_in[9];
    const int*   es    = (const int*)d_in[10];
    const int*   ed    = (const int*)d_in[11];
    float* out = (float*)d_out;

    bf16_t* W1T = (bf16_t*)d_ws;                      // 512*128
    bf16_t* W2T = W1T + 512 * 128;                    // 128*512
    bf16_t* WpT = W2T + 128 * 512;                    // 128*128
    unsigned short* zb = (unsigned short*)(WpT + 128 * 128);  // N*128 bf16
    float* el = (float*)(zb + (size_t)N_NODES * 128); // N*8
    float* er = el + N_NODES * 8;                     // N*8
    int* counts  = (int*)(er + N_NODES * 8);          // N
    int* csr_off = counts + N_NODES;                  // N+1
    int* csr_src = csr_off + N_NODES + 1;             // E
    int* rank    = csr_src + E_EDGES;                 // E
    int* bsum    = rank + E_EDGES;                    // 128
    int* boff    = bsum + 128;                        // 128
    unsigned short* lnbuf = (unsigned short*)(boff + 128);  // N*128 bf16

    k_prep<<<dim3(256), dim3(256), 0, stream>>>(W1, W2, Wfc, W1T, W2T, WpT, counts);
    k_count<<<dim3((E_EDGES + 255) / 256), dim3(256), 0, stream>>>(ed, counts, rank);
    k_scan1<<<dim3(SCAN_BLOCKS), dim3(512), 0, stream>>>(counts, bsum);
    k_scan2<<<dim3(1), dim3(128), 0, stream>>>(bsum, boff);
    k_scan3<<<dim3(SCAN_BLOCKS), dim3(512), 0, stream>>>(counts, boff, csr_off);
    k_fillproj<<<dim3(PROJ_BLOCKS + FILL_BLOCKS), dim3(512), 0, stream>>>(
        x, WpT, a_l, a_r, zb, el, er, es, ed, rank, csr_off, csr_src);
    k_node<<<dim3(N_NODES / 8), dim3(256), 0, stream>>>(csr_off, csr_src, el, er, zb, x,
                                                        gamma, beta, lnbuf, out);
    k_ffn<<<dim3(FFN_GRID), dim3(256), 0, stream>>>(W1T, b1, W2T, b2, lnbuf, out);
}